// Round 4
// baseline (3646.494 us; speedup 1.0000x reference)
//
#include <hip/hip_runtime.h>
#include <hip/hip_bf16.h>
#include <hip/hip_cooperative_groups.h>
#include <math.h>

namespace cg = cooperative_groups;

typedef __hip_bfloat16 bf16;
typedef __attribute__((ext_vector_type(8))) __bf16 bf16x8;
typedef __attribute__((ext_vector_type(4))) float f32x4;

#define NN   4096
#define BB   8
#define DD   8
#define SS   16
#define KSUB 4
#define IND  16

__device__ __forceinline__ float fsig(float x) {
    return __builtin_amdgcn_rcpf(1.f + __expf(-x));
}
__device__ __forceinline__ float ftanh(float x) {
    x = fminf(fmaxf(x, -15.f), 15.f);
    float e = __expf(2.f * x);
    return (e - 1.f) * __builtin_amdgcn_rcpf(e + 1.f);
}

// ---------------------------------------------------------------------------
// A (fp32) -> Ab (bf16), 8 elems/thread
// ---------------------------------------------------------------------------
__global__ __launch_bounds__(256) void k_convA(const float* __restrict__ A,
                                               bf16* __restrict__ Ab) {
    size_t i = ((size_t)blockIdx.x * 256 + threadIdx.x) * 8;
    float4 v0 = *reinterpret_cast<const float4*>(A + i);
    float4 v1 = *reinterpret_cast<const float4*>(A + i + 4);
    bf16 o[8];
    o[0] = __float2bfloat16(v0.x); o[1] = __float2bfloat16(v0.y);
    o[2] = __float2bfloat16(v0.z); o[3] = __float2bfloat16(v0.w);
    o[4] = __float2bfloat16(v1.x); o[5] = __float2bfloat16(v1.y);
    o[6] = __float2bfloat16(v1.z); o[7] = __float2bfloat16(v1.w);
    *reinterpret_cast<ulonglong2*>(&Ab[i]) = *reinterpret_cast<const ulonglong2*>(o);
}

// ---------------------------------------------------------------------------
// Persistent cooperative kernel: prep + 60 substeps, grid.sync between.
// 256 WGs x 1024 threads (1 WG/CU).
// ---------------------------------------------------------------------------
struct PArgs {
    const bf16*  Ab;
    const float* times; const float* x_all; const float* z_all; const float* h0;
    const float* dW1; const float* db1; const float* dW2; const float* db2;
    const float* fW1; const float* fb1; const float* fW2; const float* fb2;
    const float* pW1; const float* pb1; const float* pW2; const float* pb2;
    float* traj;
    float* hf0; float* hf1; bf16* hb0; bf16* hb1;
};

__global__ __launch_bounds__(1024) void k_persist(PArgs p) {
    cg::grid_group grid = cg::this_grid();

    __shared__ float ls_part[8][16][68];    // 34.8 KB
    __shared__ float ls_hold[16][68];       // 4.35 KB
    __shared__ float ls_dW1T[64][12]; __shared__ float ls_fW1T[64][12];  // [j][d]
    __shared__ float ls_dW2[64][8];   __shared__ float ls_fW2[64][8];
    __shared__ float ls_pW1T[64][24]; __shared__ float ls_pW2[64][8];
    __shared__ float ls_db1[64];  __shared__ float ls_fb1[64];  __shared__ float ls_pb1[64];
    __shared__ float ls_db2[8];   __shared__ float ls_fb2[8];   __shared__ float ls_pb2[8];
    __shared__ float ls_times[SS];

    const int tid = threadIdx.x;
    const int wg  = blockIdx.x;                          // 256 WGs
    const int i0  = (((wg & 7) << 5) | (wg >> 3)) << 4;  // XCD-contiguous 16-node tile

    // ---- stage all weights once ----
    for (int idx = tid; idx < 9*64; idx += 1024) {
        int d = idx >> 6, j = idx & 63;
        ls_dW1T[j][d] = p.dW1[idx]; ls_fW1T[j][d] = p.fW1[idx];
    }
    for (int idx = tid; idx < 64*8; idx += 1024) {
        ls_dW2[idx>>3][idx&7] = p.dW2[idx]; ls_fW2[idx>>3][idx&7] = p.fW2[idx];
        ls_pW2[idx>>3][idx&7] = p.pW2[idx];
    }
    for (int idx = tid; idx < 24*64; idx += 1024) ls_pW1T[idx&63][idx>>6] = p.pW1[idx];
    if (tid < 64) { ls_db1[tid] = p.db1[tid]; ls_fb1[tid] = p.fb1[tid]; ls_pb1[tid] = p.pb1[tid]; }
    else if (tid < 72) { ls_db2[tid-64] = p.db2[tid-64]; ls_fb2[tid-64] = p.fb2[tid-64]; ls_pb2[tid-64] = p.pb2[tid-64]; }
    else if (tid >= 128 && tid < 128 + SS) ls_times[tid-128] = p.times[tid-128];
    __syncthreads();

    // ---- prep: traj[0] = h0 ; state0 = h0 + pert(x[0], h0) ----
    {
        const int gidx = wg * 1024 + tid;                // row = b*NN + n
        if (gidx < BB*NN) {
            const int b = gidx >> 12, n = gidx & (NN-1);
            const float4* hp = reinterpret_cast<const float4*>(p.h0 + (size_t)gidx*8);
            float4 h0a = hp[0], h0b = hp[1];
            float hv[8] = {h0a.x,h0a.y,h0a.z,h0a.w,h0b.x,h0b.y,h0b.z,h0b.w};
            float4* tp = reinterpret_cast<float4*>(p.traj + (size_t)gidx*8);
            tp[0] = h0a; tp[1] = h0b;

            float xin[24];
            const float4* xp = reinterpret_cast<const float4*>(p.x_all + (size_t)gidx*IND);
            float4 x0=xp[0], x1=xp[1], x2=xp[2], x3=xp[3];
            xin[0]=x0.x; xin[1]=x0.y; xin[2]=x0.z; xin[3]=x0.w;
            xin[4]=x1.x; xin[5]=x1.y; xin[6]=x1.z; xin[7]=x1.w;
            xin[8]=x2.x; xin[9]=x2.y; xin[10]=x2.z; xin[11]=x2.w;
            xin[12]=x3.x; xin[13]=x3.y; xin[14]=x3.z; xin[15]=x3.w;
#pragma unroll
            for (int d = 0; d < 8; ++d) xin[16+d] = hv[d];

            float ap[8] = {0,0,0,0,0,0,0,0};
            for (int j = 0; j < 64; ++j) {
                float s1 = ls_pb1[j];
#pragma unroll
                for (int c4 = 0; c4 < 6; ++c4) {
                    f32x4 wv = *reinterpret_cast<const f32x4*>(&ls_pW1T[j][c4*4]);
#pragma unroll
                    for (int r = 0; r < 4; ++r) s1 += xin[c4*4+r] * wv[r];
                }
                s1 = fmaxf(s1, 0.f);
                f32x4 w2a = *reinterpret_cast<const f32x4*>(&ls_pW2[j][0]);
                f32x4 w2b = *reinterpret_cast<const f32x4*>(&ls_pW2[j][4]);
#pragma unroll
                for (int r = 0; r < 4; ++r) { ap[r] += s1*w2a[r]; ap[4+r] += s1*w2b[r]; }
            }
#pragma unroll
            for (int d = 0; d < 8; ++d) {
                float hf_ = hv[d] + ap[d] + ls_pb2[d];
                p.hf0[(size_t)(b*8+d)*NN + n] = hf_;
                p.hb0[(size_t)(b*8+d)*NN + n] = __float2bfloat16(hf_);
            }
        }
    }
    grid.sync();

    // ---- 60 substeps ----
    for (int g = 0; g < (SS-1)*KSUB; ++g) {
        const int s = g >> 2, k = g & 3;
        const int rbuf = g & 1;
        const float* hf_in = rbuf ? p.hf1 : p.hf0;
        const bf16*  hb_in = rbuf ? p.hb1 : p.hb0;
        float* hf_out = rbuf ? p.hf0 : p.hf1;
        bf16*  hb_out = rbuf ? p.hb0 : p.hb1;

        { // stage h_old tile: ls_hold[node][c]
            int n = tid & 15, c0 = tid >> 4;
            ls_hold[n][c0] = hf_in[(size_t)c0*NN + i0 + n];
        }

        const float t0 = ls_times[s], t1 = ls_times[s+1];
        const float dt = (t1 - t0) * 0.25f;
        const float tk = t0 + (float)k * dt;
        const float sqdt = sqrtf(dt);
        const bool dopert = (k == 3) && (s < SS - 2);

        // ---- GEMM: h_graph partials; wave = 256-wide K chunk ----
        {
            const int wave = tid >> 6, lane = tid & 63;
            const int k0 = wave << 8;
            const int lrow = lane & 15, lkk = (lane >> 4) << 3;
            const bf16* pb = p.Ab + (size_t)(i0 + lrow)*NN + k0 + lkk;   // A rows (B op)
            const bf16* pa = hb_in + (size_t)lrow*NN       + k0 + lkk;   // Ht rows (A op)
            f32x4 acc[4];
#pragma unroll
            for (int ct = 0; ct < 4; ++ct) acc[ct] = (f32x4){0.f,0.f,0.f,0.f};
#pragma unroll 4
            for (int kk = 0; kk < 8; ++kk) {
                bf16x8 bfr = *reinterpret_cast<const bf16x8*>(pb + kk*32);
#pragma unroll
                for (int ct = 0; ct < 4; ++ct) {
                    bf16x8 afr = *reinterpret_cast<const bf16x8*>(pa + ct*16*NN + kk*32);
                    acc[ct] = __builtin_amdgcn_mfma_f32_16x16x32_bf16(afr, bfr, acc[ct], 0, 0, 0);
                }
            }
            const int rb = (lane >> 4) << 2;
            if (wave < 8) {
#pragma unroll
                for (int ct = 0; ct < 4; ++ct)
#pragma unroll
                    for (int r = 0; r < 4; ++r)
                        ls_part[wave][lrow][ct*16 + rb + r] = acc[ct][r];
            }
            __syncthreads();
            if (wave >= 8) {
#pragma unroll
                for (int ct = 0; ct < 4; ++ct)
#pragma unroll
                    for (int r = 0; r < 4; ++r)
                        ls_part[wave-8][lrow][ct*16 + rb + r] += acc[ct][r];
            }
            __syncthreads();
        }

        // ---- per-(b,node) MLPs: 8 threads/row, interleaved j ----
        const int q = tid & 7, row = tid >> 3;     // row 0..127
        const int node = row & 15, b = row >> 4;
        float ing[9], inh[9];
        {
            f32x4 g0 = (f32x4){0,0,0,0}, g1 = (f32x4){0,0,0,0};
#pragma unroll
            for (int w = 0; w < 8; ++w) {
                g0 += *reinterpret_cast<const f32x4*>(&ls_part[w][node][b*8]);
                g1 += *reinterpret_cast<const f32x4*>(&ls_part[w][node][b*8+4]);
            }
            f32x4 h0v = *reinterpret_cast<const f32x4*>(&ls_hold[node][b*8]);
            f32x4 h1v = *reinterpret_cast<const f32x4*>(&ls_hold[node][b*8+4]);
#pragma unroll
            for (int r = 0; r < 4; ++r) {
                ing[r] = g0[r]; ing[4+r] = g1[r];
                inh[r] = h0v[r]; inh[4+r] = h1v[r];
            }
        }
        ing[8] = tk; inh[8] = tk;
        float adr[8] = {0,0,0,0,0,0,0,0}, adf[8] = {0,0,0,0,0,0,0,0};
#pragma unroll
        for (int jj = 0; jj < 8; ++jj) {
            const int j = q + (jj << 3);
            f32x4 w1a = *reinterpret_cast<const f32x4*>(&ls_dW1T[j][0]);
            f32x4 w1b = *reinterpret_cast<const f32x4*>(&ls_dW1T[j][4]);
            float w1t = ls_dW1T[j][8];
            f32x4 v1a = *reinterpret_cast<const f32x4*>(&ls_fW1T[j][0]);
            f32x4 v1b = *reinterpret_cast<const f32x4*>(&ls_fW1T[j][4]);
            float v1t = ls_fW1T[j][8];
            float s1 = ls_db1[j], s2 = ls_fb1[j];
#pragma unroll
            for (int r = 0; r < 4; ++r) {
                s1 += ing[r]*w1a[r] + ing[4+r]*w1b[r];
                s2 += inh[r]*v1a[r] + inh[4+r]*v1b[r];
            }
            s1 += ing[8]*w1t; s2 += inh[8]*v1t;
            float th = ftanh(s1), sg = fsig(s2);
            f32x4 w2a = *reinterpret_cast<const f32x4*>(&ls_dW2[j][0]);
            f32x4 w2b = *reinterpret_cast<const f32x4*>(&ls_dW2[j][4]);
            f32x4 v2a = *reinterpret_cast<const f32x4*>(&ls_fW2[j][0]);
            f32x4 v2b = *reinterpret_cast<const f32x4*>(&ls_fW2[j][4]);
#pragma unroll
            for (int r = 0; r < 4; ++r) {
                adr[r] += th*w2a[r]; adr[4+r] += th*w2b[r];
                adf[r] += sg*v2a[r]; adf[4+r] += sg*v2b[r];
            }
        }
#pragma unroll
        for (int d = 0; d < 8; ++d) {
            adr[d] += __shfl_xor(adr[d], 1); adr[d] += __shfl_xor(adr[d], 2); adr[d] += __shfl_xor(adr[d], 4);
            adf[d] += __shfl_xor(adf[d], 1); adf[d] += __shfl_xor(adf[d], 2); adf[d] += __shfl_xor(adf[d], 4);
        }
        const size_t zbase = ((size_t)(g*BB + b))*((size_t)NN*DD) + (size_t)(i0+node)*DD;
        float4 z0 = *reinterpret_cast<const float4*>(p.z_all + zbase);
        float4 z1 = *reinterpret_cast<const float4*>(p.z_all + zbase + 4);
        float zz[8] = {z0.x, z0.y, z0.z, z0.w, z1.x, z1.y, z1.z, z1.w};
        float hnew[8];
#pragma unroll
        for (int d = 0; d < 8; ++d) {
            float dr  = adr[d] + ls_db2[d];
            float dif = 0.1f * fsig(adf[d] + ls_fb2[d]);
            hnew[d] = inh[d] + dr * dt + dif * (sqdt * zz[d]);
        }

        if (k == 3) {
            p.traj[((size_t)((s+1)*BB + b))*((size_t)NN*DD) + (size_t)(i0+node)*DD + q] = hnew[q];
        }
        float outv;
        if (dopert) {
            float xin[24];
            const float* xp = p.x_all + ((size_t)(s+1)*BB + b)*((size_t)NN*IND) + (size_t)(i0+node)*IND;
            float4 x0 = *reinterpret_cast<const float4*>(xp);
            float4 x1 = *reinterpret_cast<const float4*>(xp + 4);
            float4 x2 = *reinterpret_cast<const float4*>(xp + 8);
            float4 x3 = *reinterpret_cast<const float4*>(xp + 12);
            xin[0]=x0.x; xin[1]=x0.y; xin[2]=x0.z; xin[3]=x0.w;
            xin[4]=x1.x; xin[5]=x1.y; xin[6]=x1.z; xin[7]=x1.w;
            xin[8]=x2.x; xin[9]=x2.y; xin[10]=x2.z; xin[11]=x2.w;
            xin[12]=x3.x; xin[13]=x3.y; xin[14]=x3.z; xin[15]=x3.w;
#pragma unroll
            for (int d = 0; d < 8; ++d) xin[16+d] = hnew[d];
            float ap[8] = {0,0,0,0,0,0,0,0};
#pragma unroll
            for (int jj = 0; jj < 8; ++jj) {
                const int j = q + (jj << 3);
                float s1 = ls_pb1[j];
#pragma unroll
                for (int c4 = 0; c4 < 6; ++c4) {
                    f32x4 wv = *reinterpret_cast<const f32x4*>(&ls_pW1T[j][c4*4]);
#pragma unroll
                    for (int r = 0; r < 4; ++r) s1 += xin[c4*4+r] * wv[r];
                }
                s1 = fmaxf(s1, 0.f);
                f32x4 w2a = *reinterpret_cast<const f32x4*>(&ls_pW2[j][0]);
                f32x4 w2b = *reinterpret_cast<const f32x4*>(&ls_pW2[j][4]);
#pragma unroll
                for (int r = 0; r < 4; ++r) { ap[r] += s1*w2a[r]; ap[4+r] += s1*w2b[r]; }
            }
            float aps[8];
#pragma unroll
            for (int d = 0; d < 8; ++d) {
                float v = ap[d];
                v += __shfl_xor(v, 1); v += __shfl_xor(v, 2); v += __shfl_xor(v, 4);
                aps[d] = v;
            }
            outv = hnew[q] + aps[q] + ls_pb2[q];
        } else {
            outv = hnew[q];
        }
        {
            const int c = b*8 + q;
            hf_out[(size_t)c*NN + i0 + node] = outv;
            hb_out[(size_t)c*NN + i0 + node] = __float2bfloat16(outv);
        }
        grid.sync();
    }
}

// ---------------------------------------------------------------------------
// readout: relu(traj @ rW1 + rb1) @ rW2 + rb2 ; 2 threads/row (16 outs each)
// ---------------------------------------------------------------------------
__global__ __launch_bounds__(256) void k_readout(
    const float* __restrict__ traj,
    const float* __restrict__ rW1, const float* __restrict__ rb1,
    const float* __restrict__ rW2, const float* __restrict__ rb2,
    float* __restrict__ outr)
{
    __shared__ float ls_W1T[64][12];   // [j][d]
    __shared__ float ls_W2[64][32];
    __shared__ float ls_b1[64];    __shared__ float ls_b2[32];
    const int tid = threadIdx.x;
    for (int idx = tid; idx < 8*64;  idx += 256) ls_W1T[idx&63][idx>>6] = rW1[idx];
    for (int idx = tid; idx < 64*32; idx += 256) ls_W2[idx>>5][idx&31] = rW2[idx];
    if (tid < 64) ls_b1[tid] = rb1[tid];
    else if (tid < 96) ls_b2[tid-64] = rb2[tid-64];
    __syncthreads();

    const int half = tid & 1, ob = half << 4;
    const size_t row = (size_t)blockIdx.x * 128 + (tid >> 1);
    const float4* pi = reinterpret_cast<const float4*>(traj + row*8);
    float4 a0 = pi[0], a1 = pi[1];
    float in[8] = {a0.x,a0.y,a0.z,a0.w,a1.x,a1.y,a1.z,a1.w};
    float out[16];
#pragma unroll
    for (int o4 = 0; o4 < 4; ++o4) {
        f32x4 bv = *reinterpret_cast<const f32x4*>(&ls_b2[ob + o4*4]);
#pragma unroll
        for (int r = 0; r < 4; ++r) out[o4*4+r] = bv[r];
    }
    for (int j = 0; j < 64; ++j) {
        f32x4 w1a = *reinterpret_cast<const f32x4*>(&ls_W1T[j][0]);
        f32x4 w1b = *reinterpret_cast<const f32x4*>(&ls_W1T[j][4]);
        float s1 = ls_b1[j];
#pragma unroll
        for (int r = 0; r < 4; ++r) s1 += in[r]*w1a[r] + in[4+r]*w1b[r];
        s1 = fmaxf(s1, 0.f);
#pragma unroll
        for (int o4 = 0; o4 < 4; ++o4) {
            f32x4 w2 = *reinterpret_cast<const f32x4*>(&ls_W2[j][ob + o4*4]);
#pragma unroll
            for (int r = 0; r < 4; ++r) out[o4*4+r] += s1 * w2[r];
        }
    }
    float* op = outr + row*32 + ob;
#pragma unroll
    for (int o4 = 0; o4 < 4; ++o4) {
        float4 v = {out[o4*4], out[o4*4+1], out[o4*4+2], out[o4*4+3]};
        *reinterpret_cast<float4*>(op + o4*4) = v;
    }
}

// ---------------------------------------------------------------------------
extern "C" void kernel_launch(void* const* d_in, const int* in_sizes, int n_in,
                              void* d_out, int out_size, void* d_ws, size_t ws_size,
                              hipStream_t stream) {
    (void)in_sizes; (void)n_in; (void)out_size; (void)ws_size;
    const float* times = (const float*)d_in[0];
    const float* x_all = (const float*)d_in[1];
    const float* h0    = (const float*)d_in[2];
    const float* Amat  = (const float*)d_in[3];
    const float* z_all = (const float*)d_in[4];
    const float* dW1 = (const float*)d_in[5],  *db1 = (const float*)d_in[6];
    const float* dW2 = (const float*)d_in[7],  *db2 = (const float*)d_in[8];
    const float* fW1 = (const float*)d_in[9],  *fb1 = (const float*)d_in[10];
    const float* fW2 = (const float*)d_in[11], *fb2 = (const float*)d_in[12];
    const float* pW1 = (const float*)d_in[13], *pb1 = (const float*)d_in[14];
    const float* pW2 = (const float*)d_in[15], *pb2 = (const float*)d_in[16];
    const float* rW1 = (const float*)d_in[17], *rb1 = (const float*)d_in[18];
    const float* rW2 = (const float*)d_in[19], *rb2 = (const float*)d_in[20];

    float* traj = (float*)d_out;                      // [16,8,4096,8]
    float* outr = traj + (size_t)SS*BB*NN*DD;         // [16,8,4096,32]

    char* ws = (char*)d_ws;
    bf16*  Ab  = (bf16*)ws;                           // 32 MB
    float* hf0 = (float*)(ws + (34u << 20));
    float* hf1 = (float*)(ws + (35u << 20));
    bf16*  hb0 = (bf16*)(ws + (36u << 20));
    bf16*  hb1 = (bf16*)(ws + (36u << 20) + (1u << 19));

    k_convA<<<NN*NN/(256*8), 256, 0, stream>>>(Amat, Ab);

    PArgs pa;
    pa.Ab = Ab; pa.times = times; pa.x_all = x_all; pa.z_all = z_all; pa.h0 = h0;
    pa.dW1 = dW1; pa.db1 = db1; pa.dW2 = dW2; pa.db2 = db2;
    pa.fW1 = fW1; pa.fb1 = fb1; pa.fW2 = fW2; pa.fb2 = fb2;
    pa.pW1 = pW1; pa.pb1 = pb1; pa.pW2 = pW2; pa.pb2 = pb2;
    pa.traj = traj; pa.hf0 = hf0; pa.hf1 = hf1; pa.hb0 = hb0; pa.hb1 = hb1;
    void* kargs[] = { (void*)&pa };
    hipLaunchCooperativeKernel(reinterpret_cast<const void*>(&k_persist),
                               dim3(NN/16), dim3(1024), kargs, 0, stream);

    k_readout<<<(SS*BB*NN)/128, 256, 0, stream>>>(traj, rW1, rb1, rW2, rb2, outr);
}

// Round 5
// 2403.873 us; speedup vs baseline: 1.5169x; 1.5169x over previous
//
#include <hip/hip_runtime.h>
#include <hip/hip_fp8.h>
#include <math.h>

typedef __attribute__((ext_vector_type(4))) float f32x4;

#define NN   4096
#define BB   8
#define DD   8
#define SS   16
#define KSUB 4
#define IND  16
#define NWG  256
#define TPB  1024
#define GSCALE 1.52587890625e-5f   // 2^-16 (A stored as fp8 of A*2^16)

__device__ __forceinline__ float fsig(float x) {
    return __builtin_amdgcn_rcpf(1.f + __expf(-x));
}
__device__ __forceinline__ float ftanh(float x) {
    x = fminf(fmaxf(x, -15.f), 15.f);
    float e = __expf(2.f * x);
    return (e - 1.f) * __builtin_amdgcn_rcpf(e + 1.f);
}
__device__ __forceinline__ unsigned char f2fp8(float x) {
    return __hip_cvt_float_to_fp8(x, __HIP_SATFINITE, __HIP_E4M3);
}

// ---------------------------------------------------------------------------
// A (fp32) -> A8 (fp8 e4m3 of A*65536), and zero the 64 barrier counters
// ---------------------------------------------------------------------------
__global__ __launch_bounds__(256) void k_convA8(const float* __restrict__ A,
                                                unsigned char* __restrict__ A8,
                                                unsigned int* __restrict__ cnt) {
    if (blockIdx.x == 0 && threadIdx.x < 64) cnt[threadIdx.x] = 0u;
    size_t i = ((size_t)blockIdx.x * 256 + threadIdx.x) * 8;
    float4 v0 = *reinterpret_cast<const float4*>(A + i);
    float4 v1 = *reinterpret_cast<const float4*>(A + i + 4);
    unsigned char o[8];
    o[0] = f2fp8(v0.x * 65536.f); o[1] = f2fp8(v0.y * 65536.f);
    o[2] = f2fp8(v0.z * 65536.f); o[3] = f2fp8(v0.w * 65536.f);
    o[4] = f2fp8(v1.x * 65536.f); o[5] = f2fp8(v1.y * 65536.f);
    o[6] = f2fp8(v1.z * 65536.f); o[7] = f2fp8(v1.w * 65536.f);
    *reinterpret_cast<unsigned long long*>(&A8[i]) =
        *reinterpret_cast<const unsigned long long*>(o);
}

// ---------------------------------------------------------------------------
// grid barrier: release-writeback + relaxed agent atomics. NO acquire/L2-inv.
// Safe because post-barrier reads are either L2-bypassing atomic loads (h8),
// immutable inputs (x/z/weights), or LDS.
// ---------------------------------------------------------------------------
__device__ __forceinline__ void gbar(unsigned int* c, int tid) {
    __syncthreads();                         // all waves' stores issued+drained
    if (tid == 0) {
        __builtin_amdgcn_fence(__ATOMIC_RELEASE, "agent");   // waitcnt + L2 writeback
        __hip_atomic_fetch_add(c, 1u, __ATOMIC_RELAXED, __HIP_MEMORY_SCOPE_AGENT);
        while (__hip_atomic_load(c, __ATOMIC_RELAXED, __HIP_MEMORY_SCOPE_AGENT) < NWG)
            __builtin_amdgcn_s_sleep(2);
    }
    __syncthreads();
    asm volatile("" ::: "memory");
}

// ---------------------------------------------------------------------------
// Persistent kernel: prep + 60 substeps. 256 WGs x 1024 thr (1 WG/CU).
// A (fp8) + h tile (fp32) live in LDS across all substeps.
// ---------------------------------------------------------------------------
struct PArgs {
    const unsigned char* A8;
    const float *times, *x_all, *z_all, *h0;
    const float *dW1, *db1, *dW2, *db2;
    const float *fW1, *fb1, *fW2, *fb2;
    const float *pW1, *pb1, *pW2, *pb2;
    float* traj;
    unsigned char* h8a; unsigned char* h8b;
    unsigned int* cnt;
};

__global__ __launch_bounds__(TPB) void k_persist(PArgs p) {
    __shared__ __align__(16) unsigned char ls_A8[16 * 4096];   // 64 KB, swizzled
    __shared__ float ls_part[8][16][68];    // 34.8 KB
    __shared__ float ls_hold[16][68];       // persistent h tile (fp32)
    __shared__ float ls_dW1T[64][12]; __shared__ float ls_fW1T[64][12];
    __shared__ float ls_dW2[64][8];   __shared__ float ls_fW2[64][8];
    __shared__ float ls_pW1T[64][24]; __shared__ float ls_pW2[64][8];
    __shared__ float ls_db1[64];  __shared__ float ls_fb1[64];  __shared__ float ls_pb1[64];
    __shared__ float ls_db2[8];   __shared__ float ls_fb2[8];   __shared__ float ls_pb2[8];
    __shared__ float ls_times[SS];

    const int tid = threadIdx.x;
    const int wg  = blockIdx.x;
    const int i0  = (((wg & 7) << 5) | (wg >> 3)) << 4;   // XCD-contiguous 16-node tile

    // ---- stage weights (once) ----
    for (int idx = tid; idx < 9*64; idx += TPB) {
        int d = idx >> 6, j = idx & 63;
        ls_dW1T[j][d] = p.dW1[idx]; ls_fW1T[j][d] = p.fW1[idx];
    }
    for (int idx = tid; idx < 64*8; idx += TPB) {
        ls_dW2[idx>>3][idx&7] = p.dW2[idx]; ls_fW2[idx>>3][idx&7] = p.fW2[idx];
        ls_pW2[idx>>3][idx&7] = p.pW2[idx];
    }
    for (int idx = tid; idx < 24*64; idx += TPB) ls_pW1T[idx&63][idx>>6] = p.pW1[idx];
    if (tid < 64) { ls_db1[tid] = p.db1[tid]; ls_fb1[tid] = p.fb1[tid]; ls_pb1[tid] = p.pb1[tid]; }
    else if (tid < 72) { ls_db2[tid-64] = p.db2[tid-64]; ls_fb2[tid-64] = p.fb2[tid-64]; ls_pb2[tid-64] = p.pb2[tid-64]; }
    else if (tid >= 128 && tid < 128 + SS) ls_times[tid-128] = p.times[tid-128];

    // ---- stage A rows into LDS (once), XOR-swizzled for conflict-free ds_read_b64 ----
    for (int it = 0; it < 8; ++it) {
        int gi = (it * TPB + tid) * 8;          // byte index within 16x4096
        int node = gi >> 12, k = gi & 4095;
        unsigned long long v = *reinterpret_cast<const unsigned long long*>(
            p.A8 + (size_t)(i0 + node) * NN + k);
        *reinterpret_cast<unsigned long long*>(
            &ls_A8[(node << 12) + (k ^ ((node & 15) << 3))]) = v;
    }
    __syncthreads();

    const int q = tid & 7, row = tid >> 3;   // 128 rows, 8 threads each
    const int node = row & 15, b = row >> 4;

    // ---- prep: traj[0] = h0 ; hold = h0 + pert(x[0], h0) ----
    {
        const float* hp = p.h0 + ((size_t)b * NN + i0 + node) * DD;
        float4 h0a = *reinterpret_cast<const float4*>(hp);
        float4 h0b = *reinterpret_cast<const float4*>(hp + 4);
        float hv[8] = {h0a.x,h0a.y,h0a.z,h0a.w,h0b.x,h0b.y,h0b.z,h0b.w};
        p.traj[((size_t)b * NN + i0 + node) * DD + q] = hv[q];

        float xin[24];
        const float* xp = p.x_all + ((size_t)b * NN + i0 + node) * IND;  // s=0
        float4 x0 = *reinterpret_cast<const float4*>(xp);
        float4 x1 = *reinterpret_cast<const float4*>(xp + 4);
        float4 x2 = *reinterpret_cast<const float4*>(xp + 8);
        float4 x3 = *reinterpret_cast<const float4*>(xp + 12);
        xin[0]=x0.x; xin[1]=x0.y; xin[2]=x0.z; xin[3]=x0.w;
        xin[4]=x1.x; xin[5]=x1.y; xin[6]=x1.z; xin[7]=x1.w;
        xin[8]=x2.x; xin[9]=x2.y; xin[10]=x2.z; xin[11]=x2.w;
        xin[12]=x3.x; xin[13]=x3.y; xin[14]=x3.z; xin[15]=x3.w;
#pragma unroll
        for (int d = 0; d < 8; ++d) xin[16+d] = hv[d];

        float ap[8] = {0,0,0,0,0,0,0,0};
#pragma unroll
        for (int jj = 0; jj < 8; ++jj) {
            const int j = q + (jj << 3);
            float s1 = ls_pb1[j];
#pragma unroll
            for (int c4 = 0; c4 < 6; ++c4) {
                f32x4 wv = *reinterpret_cast<const f32x4*>(&ls_pW1T[j][c4*4]);
#pragma unroll
                for (int r = 0; r < 4; ++r) s1 += xin[c4*4+r] * wv[r];
            }
            s1 = fmaxf(s1, 0.f);
            f32x4 w2a = *reinterpret_cast<const f32x4*>(&ls_pW2[j][0]);
            f32x4 w2b = *reinterpret_cast<const f32x4*>(&ls_pW2[j][4]);
#pragma unroll
            for (int r = 0; r < 4; ++r) { ap[r] += s1*w2a[r]; ap[4+r] += s1*w2b[r]; }
        }
        float v = ap[q];
        // butterfly each d separately (need only d=q at the end)
        float aps[8];
#pragma unroll
        for (int d = 0; d < 8; ++d) {
            float t = ap[d];
            t += __shfl_xor(t, 1); t += __shfl_xor(t, 2); t += __shfl_xor(t, 4);
            aps[d] = t;
        }
        (void)v;
        float outp = hv[q] + aps[q] + ls_pb2[q];
        ls_hold[node][b*8 + q] = outp;
        p.h8a[(size_t)(b*8 + q) * NN + i0 + node] = f2fp8(outp);
    }
    gbar(&p.cnt[0], tid);

    // ---- 60 substeps ----
    for (int g = 0; g < (SS-1)*KSUB; ++g) {
        const int s = g >> 2, k = g & 3;
        const unsigned char* hin  = (g & 1) ? p.h8b : p.h8a;
        unsigned char*       hout = (g & 1) ? p.h8a : p.h8b;

        const float t0 = ls_times[s], t1 = ls_times[s+1];
        const float dt = (t1 - t0) * 0.25f;
        const float tk = t0 + (float)k * dt;
        const float sqdt = sqrtf(dt);
        const bool dopert = (k == 3) && (s < SS - 2);

        // ---- GEMM: h_graph partials; wave = 256-wide K chunk, fp8 MFMA ----
        {
            const int wave = tid >> 6, lane = tid & 63;
            const int k0 = wave << 8;
            const int lrow = lane & 15;
            const int ksub = (lane >> 4) << 3;
            const int abase = lrow << 12;
            const int axor  = (lrow & 15) << 3;
            f32x4 acc[4];
#pragma unroll
            for (int ct = 0; ct < 4; ++ct) acc[ct] = (f32x4){0.f,0.f,0.f,0.f};
#pragma unroll
            for (int kk = 0; kk < 8; ++kk) {
                const int koff = k0 + kk*32 + ksub;
                long bfr = *reinterpret_cast<const long*>(&ls_A8[abase + (koff ^ axor)]);
#pragma unroll
                for (int ct = 0; ct < 4; ++ct) {
                    unsigned long long av = __hip_atomic_load(
                        reinterpret_cast<const unsigned long long*>(
                            hin + (size_t)(ct*16 + lrow)*NN + koff),
                        __ATOMIC_RELAXED, __HIP_MEMORY_SCOPE_AGENT);
                    acc[ct] = __builtin_amdgcn_mfma_f32_16x16x32_fp8_fp8(
                        (long)av, bfr, acc[ct], 0, 0, 0);
                }
            }
            const int rb = (lane >> 4) << 2;
            if (wave < 8) {
#pragma unroll
                for (int ct = 0; ct < 4; ++ct)
#pragma unroll
                    for (int r = 0; r < 4; ++r)
                        ls_part[wave][lrow][ct*16 + rb + r] = acc[ct][r];
            }
            __syncthreads();
            if (wave >= 8) {
#pragma unroll
                for (int ct = 0; ct < 4; ++ct)
#pragma unroll
                    for (int r = 0; r < 4; ++r)
                        ls_part[wave-8][lrow][ct*16 + rb + r] += acc[ct][r];
            }
            __syncthreads();
        }

        // ---- per-(b,node) MLPs: 8 threads/row ----
        float ing[9], inh[9];
        {
            f32x4 g0 = (f32x4){0,0,0,0}, g1 = (f32x4){0,0,0,0};
#pragma unroll
            for (int w = 0; w < 8; ++w) {
                g0 += *reinterpret_cast<const f32x4*>(&ls_part[w][node][b*8]);
                g1 += *reinterpret_cast<const f32x4*>(&ls_part[w][node][b*8+4]);
            }
            f32x4 h0v = *reinterpret_cast<const f32x4*>(&ls_hold[node][b*8]);
            f32x4 h1v = *reinterpret_cast<const f32x4*>(&ls_hold[node][b*8+4]);
#pragma unroll
            for (int r = 0; r < 4; ++r) {
                ing[r] = g0[r]*GSCALE; ing[4+r] = g1[r]*GSCALE;
                inh[r] = h0v[r];       inh[4+r] = h1v[r];
            }
        }
        ing[8] = tk; inh[8] = tk;
        float adr[8] = {0,0,0,0,0,0,0,0}, adf[8] = {0,0,0,0,0,0,0,0};
#pragma unroll
        for (int jj = 0; jj < 8; ++jj) {
            const int j = q + (jj << 3);
            f32x4 w1a = *reinterpret_cast<const f32x4*>(&ls_dW1T[j][0]);
            f32x4 w1b = *reinterpret_cast<const f32x4*>(&ls_dW1T[j][4]);
            float w1t = ls_dW1T[j][8];
            f32x4 v1a = *reinterpret_cast<const f32x4*>(&ls_fW1T[j][0]);
            f32x4 v1b = *reinterpret_cast<const f32x4*>(&ls_fW1T[j][4]);
            float v1t = ls_fW1T[j][8];
            float s1 = ls_db1[j], s2 = ls_fb1[j];
#pragma unroll
            for (int r = 0; r < 4; ++r) {
                s1 += ing[r]*w1a[r] + ing[4+r]*w1b[r];
                s2 += inh[r]*v1a[r] + inh[4+r]*v1b[r];
            }
            s1 += ing[8]*w1t; s2 += inh[8]*v1t;
            float th = ftanh(s1), sg = fsig(s2);
            f32x4 w2a = *reinterpret_cast<const f32x4*>(&ls_dW2[j][0]);
            f32x4 w2b = *reinterpret_cast<const f32x4*>(&ls_dW2[j][4]);
            f32x4 v2a = *reinterpret_cast<const f32x4*>(&ls_fW2[j][0]);
            f32x4 v2b = *reinterpret_cast<const f32x4*>(&ls_fW2[j][4]);
#pragma unroll
            for (int r = 0; r < 4; ++r) {
                adr[r] += th*w2a[r]; adr[4+r] += th*w2b[r];
                adf[r] += sg*v2a[r]; adf[4+r] += sg*v2b[r];
            }
        }
#pragma unroll
        for (int d = 0; d < 8; ++d) {
            adr[d] += __shfl_xor(adr[d], 1); adr[d] += __shfl_xor(adr[d], 2); adr[d] += __shfl_xor(adr[d], 4);
            adf[d] += __shfl_xor(adf[d], 1); adf[d] += __shfl_xor(adf[d], 2); adf[d] += __shfl_xor(adf[d], 4);
        }
        const size_t zbase = ((size_t)(g*BB + b))*((size_t)NN*DD) + (size_t)(i0+node)*DD;
        float4 z0 = *reinterpret_cast<const float4*>(p.z_all + zbase);
        float4 z1 = *reinterpret_cast<const float4*>(p.z_all + zbase + 4);
        float zz[8] = {z0.x, z0.y, z0.z, z0.w, z1.x, z1.y, z1.z, z1.w};
        float hnew[8];
#pragma unroll
        for (int d = 0; d < 8; ++d) {
            float dr  = adr[d] + ls_db2[d];
            float dif = 0.1f * fsig(adf[d] + ls_fb2[d]);
            hnew[d] = inh[d] + dr * dt + dif * (sqdt * zz[d]);
        }

        if (k == 3) {
            p.traj[((size_t)((s+1)*BB + b))*((size_t)NN*DD) + (size_t)(i0+node)*DD + q] = hnew[q];
        }
        float outv;
        if (dopert) {
            float xin[24];
            const float* xp = p.x_all + ((size_t)(s+1)*BB + b)*((size_t)NN*IND) + (size_t)(i0+node)*IND;
            float4 x0 = *reinterpret_cast<const float4*>(xp);
            float4 x1 = *reinterpret_cast<const float4*>(xp + 4);
            float4 x2 = *reinterpret_cast<const float4*>(xp + 8);
            float4 x3 = *reinterpret_cast<const float4*>(xp + 12);
            xin[0]=x0.x; xin[1]=x0.y; xin[2]=x0.z; xin[3]=x0.w;
            xin[4]=x1.x; xin[5]=x1.y; xin[6]=x1.z; xin[7]=x1.w;
            xin[8]=x2.x; xin[9]=x2.y; xin[10]=x2.z; xin[11]=x2.w;
            xin[12]=x3.x; xin[13]=x3.y; xin[14]=x3.z; xin[15]=x3.w;
#pragma unroll
            for (int d = 0; d < 8; ++d) xin[16+d] = hnew[d];
            float ap[8] = {0,0,0,0,0,0,0,0};
#pragma unroll
            for (int jj = 0; jj < 8; ++jj) {
                const int j = q + (jj << 3);
                float s1 = ls_pb1[j];
#pragma unroll
                for (int c4 = 0; c4 < 6; ++c4) {
                    f32x4 wv = *reinterpret_cast<const f32x4*>(&ls_pW1T[j][c4*4]);
#pragma unroll
                    for (int r = 0; r < 4; ++r) s1 += xin[c4*4+r] * wv[r];
                }
                s1 = fmaxf(s1, 0.f);
                f32x4 w2a = *reinterpret_cast<const f32x4*>(&ls_pW2[j][0]);
                f32x4 w2b = *reinterpret_cast<const f32x4*>(&ls_pW2[j][4]);
#pragma unroll
                for (int r = 0; r < 4; ++r) { ap[r] += s1*w2a[r]; ap[4+r] += s1*w2b[r]; }
            }
            float aps[8];
#pragma unroll
            for (int d = 0; d < 8; ++d) {
                float t = ap[d];
                t += __shfl_xor(t, 1); t += __shfl_xor(t, 2); t += __shfl_xor(t, 4);
                aps[d] = t;
            }
            outv = hnew[q] + aps[q] + ls_pb2[q];
        } else {
            outv = hnew[q];
        }
        ls_hold[node][b*8 + q] = outv;
        hout[(size_t)(b*8 + q) * NN + i0 + node] = f2fp8(outv);

        if (g < (SS-1)*KSUB - 1) gbar(&p.cnt[g+1], tid);
    }
}

// ---------------------------------------------------------------------------
// readout: relu(traj @ rW1 + rb1) @ rW2 + rb2 ; 2 threads/row (16 outs each)
// ---------------------------------------------------------------------------
__global__ __launch_bounds__(256) void k_readout(
    const float* __restrict__ traj,
    const float* __restrict__ rW1, const float* __restrict__ rb1,
    const float* __restrict__ rW2, const float* __restrict__ rb2,
    float* __restrict__ outr)
{
    __shared__ float ls_W1T[64][12];
    __shared__ float ls_W2[64][32];
    __shared__ float ls_b1[64];    __shared__ float ls_b2[32];
    const int tid = threadIdx.x;
    for (int idx = tid; idx < 8*64;  idx += 256) ls_W1T[idx&63][idx>>6] = rW1[idx];
    for (int idx = tid; idx < 64*32; idx += 256) ls_W2[idx>>5][idx&31] = rW2[idx];
    if (tid < 64) ls_b1[tid] = rb1[tid];
    else if (tid < 96) ls_b2[tid-64] = rb2[tid-64];
    __syncthreads();

    const int half = tid & 1, ob = half << 4;
    const size_t row = (size_t)blockIdx.x * 128 + (tid >> 1);
    const float4* pi = reinterpret_cast<const float4*>(traj + row*8);
    float4 a0 = pi[0], a1 = pi[1];
    float in[8] = {a0.x,a0.y,a0.z,a0.w,a1.x,a1.y,a1.z,a1.w};
    float out[16];
#pragma unroll
    for (int o4 = 0; o4 < 4; ++o4) {
        f32x4 bv = *reinterpret_cast<const f32x4*>(&ls_b2[ob + o4*4]);
#pragma unroll
        for (int r = 0; r < 4; ++r) out[o4*4+r] = bv[r];
    }
    for (int j = 0; j < 64; ++j) {
        f32x4 w1a = *reinterpret_cast<const f32x4*>(&ls_W1T[j][0]);
        f32x4 w1b = *reinterpret_cast<const f32x4*>(&ls_W1T[j][4]);
        float s1 = ls_b1[j];
#pragma unroll
        for (int r = 0; r < 4; ++r) s1 += in[r]*w1a[r] + in[4+r]*w1b[r];
        s1 = fmaxf(s1, 0.f);
#pragma unroll
        for (int o4 = 0; o4 < 4; ++o4) {
            f32x4 w2 = *reinterpret_cast<const f32x4*>(&ls_W2[j][ob + o4*4]);
#pragma unroll
            for (int r = 0; r < 4; ++r) out[o4*4+r] += s1 * w2[r];
        }
    }
    float* op = outr + row*32 + ob;
#pragma unroll
    for (int o4 = 0; o4 < 4; ++o4) {
        float4 v = {out[o4*4], out[o4*4+1], out[o4*4+2], out[o4*4+3]};
        *reinterpret_cast<float4*>(op + o4*4) = v;
    }
}

// ---------------------------------------------------------------------------
extern "C" void kernel_launch(void* const* d_in, const int* in_sizes, int n_in,
                              void* d_out, int out_size, void* d_ws, size_t ws_size,
                              hipStream_t stream) {
    (void)in_sizes; (void)n_in; (void)out_size; (void)ws_size;
    const float* times = (const float*)d_in[0];
    const float* x_all = (const float*)d_in[1];
    const float* h0    = (const float*)d_in[2];
    const float* Amat  = (const float*)d_in[3];
    const float* z_all = (const float*)d_in[4];
    const float* dW1 = (const float*)d_in[5],  *db1 = (const float*)d_in[6];
    const float* dW2 = (const float*)d_in[7],  *db2 = (const float*)d_in[8];
    const float* fW1 = (const float*)d_in[9],  *fb1 = (const float*)d_in[10];
    const float* fW2 = (const float*)d_in[11], *fb2 = (const float*)d_in[12];
    const float* pW1 = (const float*)d_in[13], *pb1 = (const float*)d_in[14];
    const float* pW2 = (const float*)d_in[15], *pb2 = (const float*)d_in[16];
    const float* rW1 = (const float*)d_in[17], *rb1 = (const float*)d_in[18];
    const float* rW2 = (const float*)d_in[19], *rb2 = (const float*)d_in[20];

    float* traj = (float*)d_out;                      // [16,8,4096,8]
    float* outr = traj + (size_t)SS*BB*NN*DD;         // [16,8,4096,32]

    char* ws = (char*)d_ws;
    unsigned char* A8  = (unsigned char*)ws;                 // 16 MB
    unsigned char* h8a = (unsigned char*)(ws + (17u << 20)); // 256 KB
    unsigned char* h8b = (unsigned char*)(ws + (17u << 20) + (1u << 19));
    unsigned int*  cnt = (unsigned int*)(ws + (18u << 20));  // 64 counters

    k_convA8<<<NN*NN/(256*8), 256, 0, stream>>>(Amat, A8, cnt);

    PArgs pa;
    pa.A8 = A8; pa.times = times; pa.x_all = x_all; pa.z_all = z_all; pa.h0 = h0;
    pa.dW1 = dW1; pa.db1 = db1; pa.dW2 = dW2; pa.db2 = db2;
    pa.fW1 = fW1; pa.fb1 = fb1; pa.fW2 = fW2; pa.fb2 = fb2;
    pa.pW1 = pW1; pa.pb1 = pb1; pa.pW2 = pW2; pa.pb2 = pb2;
    pa.traj = traj; pa.h8a = h8a; pa.h8b = h8b; pa.cnt = cnt;
    k_persist<<<NWG, TPB, 0, stream>>>(pa);

    k_readout<<<(SS*BB*NN)/128, 256, 0, stream>>>(traj, rW1, rb1, rW2, rb2, outr);
}

// Round 6
// 2201.193 us; speedup vs baseline: 1.6566x; 1.0921x over previous
//
#include <hip/hip_runtime.h>
#include <hip/hip_fp8.h>
#include <math.h>

typedef __attribute__((ext_vector_type(4))) float f32x4;

#define NN   4096
#define BB   8
#define DD   8
#define SS   16
#define KSUB 4
#define IND  16
#define NWG  256
#define TPB  1024
#define HSZ  (64 * 4096)           // one rotating h buffer (fp8), 256 KB
#define GSCALE 1.52587890625e-5f   // 2^-16 (A stored as fp8 of A*2^16)

__device__ __forceinline__ float fsig(float x) {
    return __builtin_amdgcn_rcpf(1.f + __expf(-x));
}
__device__ __forceinline__ float ftanh(float x) {
    x = fminf(fmaxf(x, -15.f), 15.f);
    float e = __expf(2.f * x);
    return (e - 1.f) * __builtin_amdgcn_rcpf(e + 1.f);
}
__device__ __forceinline__ unsigned char f2fp8(float x) {
    return __hip_cvt_float_to_fp8(x, __HIP_SATFINITE, __HIP_E4M3);
}

// ---------------------------------------------------------------------------
// A (fp32) -> A8 (fp8 e4m3 of A*65536), and zero the 64 barrier counters
// ---------------------------------------------------------------------------
__global__ __launch_bounds__(256) void k_convA8(const float* __restrict__ A,
                                                unsigned char* __restrict__ A8,
                                                unsigned int* __restrict__ cnt) {
    if (blockIdx.x == 0 && threadIdx.x < 64) cnt[threadIdx.x] = 0u;
    size_t i = ((size_t)blockIdx.x * 256 + threadIdx.x) * 8;
    float4 v0 = *reinterpret_cast<const float4*>(A + i);
    float4 v1 = *reinterpret_cast<const float4*>(A + i + 4);
    unsigned char o[8];
    o[0] = f2fp8(v0.x * 65536.f); o[1] = f2fp8(v0.y * 65536.f);
    o[2] = f2fp8(v0.z * 65536.f); o[3] = f2fp8(v0.w * 65536.f);
    o[4] = f2fp8(v1.x * 65536.f); o[5] = f2fp8(v1.y * 65536.f);
    o[6] = f2fp8(v1.z * 65536.f); o[7] = f2fp8(v1.w * 65536.f);
    *reinterpret_cast<unsigned long long*>(&A8[i]) =
        *reinterpret_cast<const unsigned long long*>(o);
}

// ---------------------------------------------------------------------------
// grid barrier: release-writeback + relaxed agent atomics on the counter only.
// h-state buffers are write-once (rotating), so post-barrier reads use plain
// cached loads: no stale line can exist for a never-touched address.
// ---------------------------------------------------------------------------
__device__ __forceinline__ void gbar(unsigned int* c, int tid) {
    __syncthreads();                         // all stores issued + drained
    if (tid == 0) {
        __builtin_amdgcn_fence(__ATOMIC_RELEASE, "agent");   // wb dirty L2 -> IF
        __hip_atomic_fetch_add(c, 1u, __ATOMIC_RELAXED, __HIP_MEMORY_SCOPE_AGENT);
        while (__hip_atomic_load(c, __ATOMIC_RELAXED, __HIP_MEMORY_SCOPE_AGENT) < NWG)
            __builtin_amdgcn_s_sleep(2);
    }
    __syncthreads();
    asm volatile("" ::: "memory");
}

// ---------------------------------------------------------------------------
// Persistent kernel: prep + 60 substeps. 256 WGs x 1024 thr (1 WG/CU).
// A (fp8) + h tile (fp32) live in LDS across all substeps; h broadcast via
// rotating write-once fp8 buffers.
// ---------------------------------------------------------------------------
struct PArgs {
    const unsigned char* A8;
    const float *times, *x_all, *z_all, *h0;
    const float *dW1, *db1, *dW2, *db2;
    const float *fW1, *fb1, *fW2, *fb2;
    const float *pW1, *pb1, *pW2, *pb2;
    float* traj;
    unsigned char* h8;       // 61 rotating buffers of HSZ
    unsigned int* cnt;
};

__global__ __launch_bounds__(TPB) void k_persist(PArgs p) {
    __shared__ __align__(16) unsigned char ls_A8[16 * 4096];   // 64 KB, swizzled
    __shared__ float ls_part[8][16][68];    // 34.8 KB
    __shared__ float ls_hold[16][68];       // persistent h tile (fp32)
    __shared__ float ls_dW1T[64][12]; __shared__ float ls_fW1T[64][12];
    __shared__ float ls_dW2[64][8];   __shared__ float ls_fW2[64][8];
    __shared__ float ls_pW1T[64][24]; __shared__ float ls_pW2[64][8];
    __shared__ float ls_db1[64];  __shared__ float ls_fb1[64];  __shared__ float ls_pb1[64];
    __shared__ float ls_db2[8];   __shared__ float ls_fb2[8];   __shared__ float ls_pb2[8];
    __shared__ float ls_times[SS];

    const int tid = threadIdx.x;
    const int wg  = blockIdx.x;
    const int i0  = (((wg & 7) << 5) | (wg >> 3)) << 4;   // XCD-contiguous 16-node tile

    // ---- stage weights (once) ----
    for (int idx = tid; idx < 9*64; idx += TPB) {
        int d = idx >> 6, j = idx & 63;
        ls_dW1T[j][d] = p.dW1[idx]; ls_fW1T[j][d] = p.fW1[idx];
    }
    for (int idx = tid; idx < 64*8; idx += TPB) {
        ls_dW2[idx>>3][idx&7] = p.dW2[idx]; ls_fW2[idx>>3][idx&7] = p.fW2[idx];
        ls_pW2[idx>>3][idx&7] = p.pW2[idx];
    }
    for (int idx = tid; idx < 24*64; idx += TPB) ls_pW1T[idx&63][idx>>6] = p.pW1[idx];
    if (tid < 64) { ls_db1[tid] = p.db1[tid]; ls_fb1[tid] = p.fb1[tid]; ls_pb1[tid] = p.pb1[tid]; }
    else if (tid < 72) { ls_db2[tid-64] = p.db2[tid-64]; ls_fb2[tid-64] = p.fb2[tid-64]; ls_pb2[tid-64] = p.pb2[tid-64]; }
    else if (tid >= 128 && tid < 128 + SS) ls_times[tid-128] = p.times[tid-128];

    // ---- stage A rows into LDS (once), XOR-swizzled ----
    for (int it = 0; it < 8; ++it) {
        int gi = (it * TPB + tid) * 8;          // byte index within 16x4096
        int node = gi >> 12, k = gi & 4095;
        unsigned long long v = *reinterpret_cast<const unsigned long long*>(
            p.A8 + (size_t)(i0 + node) * NN + k);
        *reinterpret_cast<unsigned long long*>(
            &ls_A8[(node << 12) + (k ^ ((node & 15) << 3))]) = v;
    }
    __syncthreads();

    const int q = tid & 7, row = tid >> 3;   // 128 rows, 8 threads each
    const int node = row & 15, b = row >> 4;

    // ---- prep: traj[0] = h0 ; hold = h0 + pert(x[0], h0) -> h8[0] ----
    {
        const float* hp = p.h0 + ((size_t)b * NN + i0 + node) * DD;
        float4 h0a = *reinterpret_cast<const float4*>(hp);
        float4 h0b = *reinterpret_cast<const float4*>(hp + 4);
        float hv[8] = {h0a.x,h0a.y,h0a.z,h0a.w,h0b.x,h0b.y,h0b.z,h0b.w};
        p.traj[((size_t)b * NN + i0 + node) * DD + q] = hv[q];

        float xin[24];
        const float* xp = p.x_all + ((size_t)b * NN + i0 + node) * IND;  // s=0
        float4 x0 = *reinterpret_cast<const float4*>(xp);
        float4 x1 = *reinterpret_cast<const float4*>(xp + 4);
        float4 x2 = *reinterpret_cast<const float4*>(xp + 8);
        float4 x3 = *reinterpret_cast<const float4*>(xp + 12);
        xin[0]=x0.x; xin[1]=x0.y; xin[2]=x0.z; xin[3]=x0.w;
        xin[4]=x1.x; xin[5]=x1.y; xin[6]=x1.z; xin[7]=x1.w;
        xin[8]=x2.x; xin[9]=x2.y; xin[10]=x2.z; xin[11]=x2.w;
        xin[12]=x3.x; xin[13]=x3.y; xin[14]=x3.z; xin[15]=x3.w;
#pragma unroll
        for (int d = 0; d < 8; ++d) xin[16+d] = hv[d];

        float ap[8] = {0,0,0,0,0,0,0,0};
#pragma unroll
        for (int jj = 0; jj < 8; ++jj) {
            const int j = q + (jj << 3);
            float s1 = ls_pb1[j];
#pragma unroll
            for (int c4 = 0; c4 < 6; ++c4) {
                f32x4 wv = *reinterpret_cast<const f32x4*>(&ls_pW1T[j][c4*4]);
#pragma unroll
                for (int r = 0; r < 4; ++r) s1 += xin[c4*4+r] * wv[r];
            }
            s1 = fmaxf(s1, 0.f);
            f32x4 w2a = *reinterpret_cast<const f32x4*>(&ls_pW2[j][0]);
            f32x4 w2b = *reinterpret_cast<const f32x4*>(&ls_pW2[j][4]);
#pragma unroll
            for (int r = 0; r < 4; ++r) { ap[r] += s1*w2a[r]; ap[4+r] += s1*w2b[r]; }
        }
        float aps[8];
#pragma unroll
        for (int d = 0; d < 8; ++d) {
            float t = ap[d];
            t += __shfl_xor(t, 1); t += __shfl_xor(t, 2); t += __shfl_xor(t, 4);
            aps[d] = t;
        }
        float outp = hv[q] + aps[q] + ls_pb2[q];
        ls_hold[node][b*8 + q] = outp;
        p.h8[(size_t)(b*8 + q) * NN + i0 + node] = f2fp8(outp);
    }
    gbar(&p.cnt[0], tid);

    // ---- 60 substeps ----
    for (int g = 0; g < (SS-1)*KSUB; ++g) {
        const int s = g >> 2, k = g & 3;
        const unsigned char* hin  = p.h8 + (size_t)g * HSZ;
        unsigned char*       hout = p.h8 + (size_t)(g+1) * HSZ;

        const float t0 = ls_times[s], t1 = ls_times[s+1];
        const float dt = (t1 - t0) * 0.25f;
        const float tk = t0 + (float)k * dt;
        const float sqdt = sqrtf(dt);
        const bool dopert = (k == 3) && (s < SS - 2);

        // ---- GEMM: h_graph partials; wave = 256-wide K chunk, fp8 MFMA ----
        {
            const int wave = tid >> 6, lane = tid & 63;
            const int k0 = wave << 8;
            const int lrow = lane & 15;
            const int ksub = (lane >> 4) << 3;
            const int abase = lrow << 12;
            const int axor  = (lrow & 15) << 3;
            f32x4 acc[4];
#pragma unroll
            for (int ct = 0; ct < 4; ++ct) acc[ct] = (f32x4){0.f,0.f,0.f,0.f};
#pragma unroll
            for (int kk = 0; kk < 8; ++kk) {
                const int koff = k0 + kk*32 + ksub;
                long bfr = *reinterpret_cast<const long*>(&ls_A8[abase + (koff ^ axor)]);
#pragma unroll
                for (int ct = 0; ct < 4; ++ct) {
                    long av = *reinterpret_cast<const long*>(
                        hin + (size_t)(ct*16 + lrow)*NN + koff);
                    acc[ct] = __builtin_amdgcn_mfma_f32_16x16x32_fp8_fp8(
                        av, bfr, acc[ct], 0, 0, 0);
                }
            }
            const int rb = (lane >> 4) << 2;
            if (wave < 8) {
#pragma unroll
                for (int ct = 0; ct < 4; ++ct)
#pragma unroll
                    for (int r = 0; r < 4; ++r)
                        ls_part[wave][lrow][ct*16 + rb + r] = acc[ct][r];
            }
            __syncthreads();
            if (wave >= 8) {
#pragma unroll
                for (int ct = 0; ct < 4; ++ct)
#pragma unroll
                    for (int r = 0; r < 4; ++r)
                        ls_part[wave-8][lrow][ct*16 + rb + r] += acc[ct][r];
            }
            __syncthreads();
        }

        // ---- per-(b,node) MLPs: 8 threads/row ----
        float ing[9], inh[9];
        {
            f32x4 g0 = (f32x4){0,0,0,0}, g1 = (f32x4){0,0,0,0};
#pragma unroll
            for (int w = 0; w < 8; ++w) {
                g0 += *reinterpret_cast<const f32x4*>(&ls_part[w][node][b*8]);
                g1 += *reinterpret_cast<const f32x4*>(&ls_part[w][node][b*8+4]);
            }
            f32x4 h0v = *reinterpret_cast<const f32x4*>(&ls_hold[node][b*8]);
            f32x4 h1v = *reinterpret_cast<const f32x4*>(&ls_hold[node][b*8+4]);
#pragma unroll
            for (int r = 0; r < 4; ++r) {
                ing[r] = g0[r]*GSCALE; ing[4+r] = g1[r]*GSCALE;
                inh[r] = h0v[r];       inh[4+r] = h1v[r];
            }
        }
        ing[8] = tk; inh[8] = tk;
        float adr[8] = {0,0,0,0,0,0,0,0}, adf[8] = {0,0,0,0,0,0,0,0};
#pragma unroll
        for (int jj = 0; jj < 8; ++jj) {
            const int j = q + (jj << 3);
            f32x4 w1a = *reinterpret_cast<const f32x4*>(&ls_dW1T[j][0]);
            f32x4 w1b = *reinterpret_cast<const f32x4*>(&ls_dW1T[j][4]);
            float w1t = ls_dW1T[j][8];
            f32x4 v1a = *reinterpret_cast<const f32x4*>(&ls_fW1T[j][0]);
            f32x4 v1b = *reinterpret_cast<const f32x4*>(&ls_fW1T[j][4]);
            float v1t = ls_fW1T[j][8];
            float s1 = ls_db1[j], s2 = ls_fb1[j];
#pragma unroll
            for (int r = 0; r < 4; ++r) {
                s1 += ing[r]*w1a[r] + ing[4+r]*w1b[r];
                s2 += inh[r]*v1a[r] + inh[4+r]*v1b[r];
            }
            s1 += ing[8]*w1t; s2 += inh[8]*v1t;
            float th = ftanh(s1), sg = fsig(s2);
            f32x4 w2a = *reinterpret_cast<const f32x4*>(&ls_dW2[j][0]);
            f32x4 w2b = *reinterpret_cast<const f32x4*>(&ls_dW2[j][4]);
            f32x4 v2a = *reinterpret_cast<const f32x4*>(&ls_fW2[j][0]);
            f32x4 v2b = *reinterpret_cast<const f32x4*>(&ls_fW2[j][4]);
#pragma unroll
            for (int r = 0; r < 4; ++r) {
                adr[r] += th*w2a[r]; adr[4+r] += th*w2b[r];
                adf[r] += sg*v2a[r]; adf[4+r] += sg*v2b[r];
            }
        }
#pragma unroll
        for (int d = 0; d < 8; ++d) {
            adr[d] += __shfl_xor(adr[d], 1); adr[d] += __shfl_xor(adr[d], 2); adr[d] += __shfl_xor(adr[d], 4);
            adf[d] += __shfl_xor(adf[d], 1); adf[d] += __shfl_xor(adf[d], 2); adf[d] += __shfl_xor(adf[d], 4);
        }
        const size_t zbase = ((size_t)(g*BB + b))*((size_t)NN*DD) + (size_t)(i0+node)*DD;
        float4 z0 = *reinterpret_cast<const float4*>(p.z_all + zbase);
        float4 z1 = *reinterpret_cast<const float4*>(p.z_all + zbase + 4);
        float zz[8] = {z0.x, z0.y, z0.z, z0.w, z1.x, z1.y, z1.z, z1.w};
        float hnew[8];
#pragma unroll
        for (int d = 0; d < 8; ++d) {
            float dr  = adr[d] + ls_db2[d];
            float dif = 0.1f * fsig(adf[d] + ls_fb2[d]);
            hnew[d] = inh[d] + dr * dt + dif * (sqdt * zz[d]);
        }

        if (k == 3) {
            p.traj[((size_t)((s+1)*BB + b))*((size_t)NN*DD) + (size_t)(i0+node)*DD + q] = hnew[q];
        }
        float outv;
        if (dopert) {
            float xin[24];
            const float* xp = p.x_all + ((size_t)(s+1)*BB + b)*((size_t)NN*IND) + (size_t)(i0+node)*IND;
            float4 x0 = *reinterpret_cast<const float4*>(xp);
            float4 x1 = *reinterpret_cast<const float4*>(xp + 4);
            float4 x2 = *reinterpret_cast<const float4*>(xp + 8);
            float4 x3 = *reinterpret_cast<const float4*>(xp + 12);
            xin[0]=x0.x; xin[1]=x0.y; xin[2]=x0.z; xin[3]=x0.w;
            xin[4]=x1.x; xin[5]=x1.y; xin[6]=x1.z; xin[7]=x1.w;
            xin[8]=x2.x; xin[9]=x2.y; xin[10]=x2.z; xin[11]=x2.w;
            xin[12]=x3.x; xin[13]=x3.y; xin[14]=x3.z; xin[15]=x3.w;
#pragma unroll
            for (int d = 0; d < 8; ++d) xin[16+d] = hnew[d];
            float ap[8] = {0,0,0,0,0,0,0,0};
#pragma unroll
            for (int jj = 0; jj < 8; ++jj) {
                const int j = q + (jj << 3);
                float s1 = ls_pb1[j];
#pragma unroll
                for (int c4 = 0; c4 < 6; ++c4) {
                    f32x4 wv = *reinterpret_cast<const f32x4*>(&ls_pW1T[j][c4*4]);
#pragma unroll
                    for (int r = 0; r < 4; ++r) s1 += xin[c4*4+r] * wv[r];
                }
                s1 = fmaxf(s1, 0.f);
                f32x4 w2a = *reinterpret_cast<const f32x4*>(&ls_pW2[j][0]);
                f32x4 w2b = *reinterpret_cast<const f32x4*>(&ls_pW2[j][4]);
#pragma unroll
                for (int r = 0; r < 4; ++r) { ap[r] += s1*w2a[r]; ap[4+r] += s1*w2b[r]; }
            }
            float aps[8];
#pragma unroll
            for (int d = 0; d < 8; ++d) {
                float t = ap[d];
                t += __shfl_xor(t, 1); t += __shfl_xor(t, 2); t += __shfl_xor(t, 4);
                aps[d] = t;
            }
            outv = hnew[q] + aps[q] + ls_pb2[q];
        } else {
            outv = hnew[q];
        }
        ls_hold[node][b*8 + q] = outv;
        hout[(size_t)(b*8 + q) * NN + i0 + node] = f2fp8(outv);

        if (g < (SS-1)*KSUB - 1) gbar(&p.cnt[g+1], tid);
    }
}

// ---------------------------------------------------------------------------
// readout: relu(traj @ rW1 + rb1) @ rW2 + rb2 ; 2 threads/row (16 outs each)
// ---------------------------------------------------------------------------
__global__ __launch_bounds__(256) void k_readout(
    const float* __restrict__ traj,
    const float* __restrict__ rW1, const float* __restrict__ rb1,
    const float* __restrict__ rW2, const float* __restrict__ rb2,
    float* __restrict__ outr)
{
    __shared__ float ls_W1T[64][12];
    __shared__ float ls_W2[64][32];
    __shared__ float ls_b1[64];    __shared__ float ls_b2[32];
    const int tid = threadIdx.x;
    for (int idx = tid; idx < 8*64;  idx += 256) ls_W1T[idx&63][idx>>6] = rW1[idx];
    for (int idx = tid; idx < 64*32; idx += 256) ls_W2[idx>>5][idx&31] = rW2[idx];
    if (tid < 64) ls_b1[tid] = rb1[tid];
    else if (tid < 96) ls_b2[tid-64] = rb2[tid-64];
    __syncthreads();

    const int half = tid & 1, ob = half << 4;
    const size_t row = (size_t)blockIdx.x * 128 + (tid >> 1);
    const float4* pi = reinterpret_cast<const float4*>(traj + row*8);
    float4 a0 = pi[0], a1 = pi[1];
    float in[8] = {a0.x,a0.y,a0.z,a0.w,a1.x,a1.y,a1.z,a1.w};
    float out[16];
#pragma unroll
    for (int o4 = 0; o4 < 4; ++o4) {
        f32x4 bv = *reinterpret_cast<const f32x4*>(&ls_b2[ob + o4*4]);
#pragma unroll
        for (int r = 0; r < 4; ++r) out[o4*4+r] = bv[r];
    }
    for (int j = 0; j < 64; ++j) {
        f32x4 w1a = *reinterpret_cast<const f32x4*>(&ls_W1T[j][0]);
        f32x4 w1b = *reinterpret_cast<const f32x4*>(&ls_W1T[j][4]);
        float s1 = ls_b1[j];
#pragma unroll
        for (int r = 0; r < 4; ++r) s1 += in[r]*w1a[r] + in[4+r]*w1b[r];
        s1 = fmaxf(s1, 0.f);
#pragma unroll
        for (int o4 = 0; o4 < 4; ++o4) {
            f32x4 w2 = *reinterpret_cast<const f32x4*>(&ls_W2[j][ob + o4*4]);
#pragma unroll
            for (int r = 0; r < 4; ++r) out[o4*4+r] += s1 * w2[r];
        }
    }
    float* op = outr + row*32 + ob;
#pragma unroll
    for (int o4 = 0; o4 < 4; ++o4) {
        float4 v = {out[o4*4], out[o4*4+1], out[o4*4+2], out[o4*4+3]};
        *reinterpret_cast<float4*>(op + o4*4) = v;
    }
}

// ---------------------------------------------------------------------------
extern "C" void kernel_launch(void* const* d_in, const int* in_sizes, int n_in,
                              void* d_out, int out_size, void* d_ws, size_t ws_size,
                              hipStream_t stream) {
    (void)in_sizes; (void)n_in; (void)out_size; (void)ws_size;
    const float* times = (const float*)d_in[0];
    const float* x_all = (const float*)d_in[1];
    const float* h0    = (const float*)d_in[2];
    const float* Amat  = (const float*)d_in[3];
    const float* z_all = (const float*)d_in[4];
    const float* dW1 = (const float*)d_in[5],  *db1 = (const float*)d_in[6];
    const float* dW2 = (const float*)d_in[7],  *db2 = (const float*)d_in[8];
    const float* fW1 = (const float*)d_in[9],  *fb1 = (const float*)d_in[10];
    const float* fW2 = (const float*)d_in[11], *fb2 = (const float*)d_in[12];
    const float* pW1 = (const float*)d_in[13], *pb1 = (const float*)d_in[14];
    const float* pW2 = (const float*)d_in[15], *pb2 = (const float*)d_in[16];
    const float* rW1 = (const float*)d_in[17], *rb1 = (const float*)d_in[18];
    const float* rW2 = (const float*)d_in[19], *rb2 = (const float*)d_in[20];

    float* traj = (float*)d_out;                      // [16,8,4096,8]
    float* outr = traj + (size_t)SS*BB*NN*DD;         // [16,8,4096,32]

    char* ws = (char*)d_ws;
    unsigned char* A8  = (unsigned char*)ws;                 // 16 MB
    unsigned char* h8  = (unsigned char*)(ws + (16u << 20)); // 61 x 256 KB
    unsigned int*  cnt = (unsigned int*)(ws + (35u << 20));  // 64 counters

    k_convA8<<<NN*NN/(256*8), 256, 0, stream>>>(Amat, A8, cnt);

    PArgs pa;
    pa.A8 = A8; pa.times = times; pa.x_all = x_all; pa.z_all = z_all; pa.h0 = h0;
    pa.dW1 = dW1; pa.db1 = db1; pa.dW2 = dW2; pa.db2 = db2;
    pa.fW1 = fW1; pa.fb1 = fb1; pa.fW2 = fW2; pa.fb2 = fb2;
    pa.pW1 = pW1; pa.pb1 = pb1; pa.pW2 = pW2; pa.pb2 = pb2;
    pa.traj = traj; pa.h8 = h8; pa.cnt = cnt;
    k_persist<<<NWG, TPB, 0, stream>>>(pa);

    k_readout<<<(SS*BB*NN)/128, 256, 0, stream>>>(traj, rW1, rb1, rW2, rb2, outr);
}

// Round 7
// 2115.915 us; speedup vs baseline: 1.7234x; 1.0403x over previous
//
#include <hip/hip_runtime.h>
#include <hip/hip_fp8.h>
#include <math.h>

typedef __attribute__((ext_vector_type(4))) float f32x4;

#define NN   4096
#define BB   8
#define DD   8
#define SS   16
#define KSUB 4
#define IND  16
#define NWG  256
#define TPB  1024
#define HSZ  (64 * 4096)           // one rotating h buffer (fp8), 256 KB
#define GSCALE 1.52587890625e-5f   // 2^-16 (A stored as fp8 of A*2^16)

__device__ __forceinline__ float fsig(float x) {
    return __builtin_amdgcn_rcpf(1.f + __expf(-x));
}
__device__ __forceinline__ float ftanh(float x) {
    x = fminf(fmaxf(x, -15.f), 15.f);
    float e = __expf(2.f * x);
    return (e - 1.f) * __builtin_amdgcn_rcpf(e + 1.f);
}
__device__ __forceinline__ unsigned char f2fp8(float x) {
    return __hip_cvt_float_to_fp8(x, __HIP_SATFINITE, __HIP_E4M3);
}

// ---------------------------------------------------------------------------
// A (fp32) -> A8 (fp8 e4m3 of A*65536), and zero the 64 barrier counters
// ---------------------------------------------------------------------------
__global__ __launch_bounds__(256) void k_convA8(const float* __restrict__ A,
                                                unsigned char* __restrict__ A8,
                                                unsigned int* __restrict__ cnt) {
    if (blockIdx.x == 0 && threadIdx.x < 64) cnt[threadIdx.x] = 0u;
    size_t i = ((size_t)blockIdx.x * 256 + threadIdx.x) * 8;
    float4 v0 = *reinterpret_cast<const float4*>(A + i);
    float4 v1 = *reinterpret_cast<const float4*>(A + i + 4);
    unsigned char o[8];
    o[0] = f2fp8(v0.x * 65536.f); o[1] = f2fp8(v0.y * 65536.f);
    o[2] = f2fp8(v0.z * 65536.f); o[3] = f2fp8(v0.w * 65536.f);
    o[4] = f2fp8(v1.x * 65536.f); o[5] = f2fp8(v1.y * 65536.f);
    o[6] = f2fp8(v1.z * 65536.f); o[7] = f2fp8(v1.w * 65536.f);
    *reinterpret_cast<unsigned long long*>(&A8[i]) =
        *reinterpret_cast<const unsigned long long*>(o);
}

// ---------------------------------------------------------------------------
// grid barrier, NO wbl2: h-state crossed XCDs via agent-scope atomic stores
// (L2-bypassing) before this; every wave drains vmcnt, then one arrive.
// Post-barrier h reads are plain cached loads of write-once addresses.
// ---------------------------------------------------------------------------
__device__ __forceinline__ void gbar2(unsigned int* c, int tid) {
    asm volatile("s_waitcnt vmcnt(0)" ::: "memory");   // every wave drains its stores
    __syncthreads();
    if (tid == 0) {
        __hip_atomic_fetch_add(c, 1u, __ATOMIC_RELAXED, __HIP_MEMORY_SCOPE_AGENT);
        while (__hip_atomic_load(c, __ATOMIC_RELAXED, __HIP_MEMORY_SCOPE_AGENT) < NWG)
            __builtin_amdgcn_s_sleep(1);
    }
    __syncthreads();
    asm volatile("" ::: "memory");
}

// ---------------------------------------------------------------------------
// Persistent kernel: prep + 60 substeps. 256 WGs x 1024 thr (1 WG/CU).
// ---------------------------------------------------------------------------
struct PArgs {
    const unsigned char* A8;
    const float *times, *x_all, *z_all, *h0;
    const float *dW1, *db1, *dW2, *db2;
    const float *fW1, *fb1, *fW2, *fb2;
    const float *pW1, *pb1, *pW2, *pb2;
    float* traj;
    unsigned char* h8;       // 61 rotating buffers of HSZ
    unsigned int* cnt;
};

__global__ __launch_bounds__(TPB) void k_persist(PArgs p) {
    __shared__ __align__(16) unsigned char ls_A8[16 * 4096];   // 64 KB, swizzled
    __shared__ float ls_part[8][16][68];    // 34.8 KB
    __shared__ float ls_hold[16][68];       // persistent h tile (fp32)
    __shared__ __align__(4) unsigned char ls_h8st[64][16];     // staging for packed h8 stores
    __shared__ float ls_dW1T[64][12]; __shared__ float ls_fW1T[64][12];
    __shared__ float ls_dW2[64][8];   __shared__ float ls_fW2[64][8];
    __shared__ float ls_pW1T[64][24]; __shared__ float ls_pW2[64][8];
    __shared__ float ls_db1[64];  __shared__ float ls_fb1[64];  __shared__ float ls_pb1[64];
    __shared__ float ls_db2[8];   __shared__ float ls_fb2[8];   __shared__ float ls_pb2[8];
    __shared__ float ls_times[SS];

    const int tid = threadIdx.x;
    const int wg  = blockIdx.x;
    const int i0  = (((wg & 7) << 5) | (wg >> 3)) << 4;   // XCD-contiguous 16-node tile

    // ---- stage weights (once) ----
    for (int idx = tid; idx < 9*64; idx += TPB) {
        int d = idx >> 6, j = idx & 63;
        ls_dW1T[j][d] = p.dW1[idx]; ls_fW1T[j][d] = p.fW1[idx];
    }
    for (int idx = tid; idx < 64*8; idx += TPB) {
        ls_dW2[idx>>3][idx&7] = p.dW2[idx]; ls_fW2[idx>>3][idx&7] = p.fW2[idx];
        ls_pW2[idx>>3][idx&7] = p.pW2[idx];
    }
    for (int idx = tid; idx < 24*64; idx += TPB) ls_pW1T[idx&63][idx>>6] = p.pW1[idx];
    if (tid < 64) { ls_db1[tid] = p.db1[tid]; ls_fb1[tid] = p.fb1[tid]; ls_pb1[tid] = p.pb1[tid]; }
    else if (tid < 72) { ls_db2[tid-64] = p.db2[tid-64]; ls_fb2[tid-64] = p.fb2[tid-64]; ls_pb2[tid-64] = p.pb2[tid-64]; }
    else if (tid >= 128 && tid < 128 + SS) ls_times[tid-128] = p.times[tid-128];

    // ---- stage A rows into LDS (once), XOR-swizzled ----
    for (int it = 0; it < 8; ++it) {
        int gi = (it * TPB + tid) * 8;          // byte index within 16x4096
        int node = gi >> 12, k = gi & 4095;
        unsigned long long v = *reinterpret_cast<const unsigned long long*>(
            p.A8 + (size_t)(i0 + node) * NN + k);
        *reinterpret_cast<unsigned long long*>(
            &ls_A8[(node << 12) + (k ^ ((node & 15) << 3))]) = v;
    }
    __syncthreads();

    const int q = tid & 7, row = tid >> 3;   // 128 rows, 8 threads each
    const int node = row & 15, b = row >> 4;

    // ---- prep: traj[0] = h0 ; hold = h0 + pert(x[0], h0) -> h8[0] ----
    {
        const float* hp = p.h0 + ((size_t)b * NN + i0 + node) * DD;
        float4 h0a = *reinterpret_cast<const float4*>(hp);
        float4 h0b = *reinterpret_cast<const float4*>(hp + 4);
        float hv[8] = {h0a.x,h0a.y,h0a.z,h0a.w,h0b.x,h0b.y,h0b.z,h0b.w};
        p.traj[((size_t)b * NN + i0 + node) * DD + q] = hv[q];

        float xin[24];
        const float* xp = p.x_all + ((size_t)b * NN + i0 + node) * IND;  // s=0
        float4 x0 = *reinterpret_cast<const float4*>(xp);
        float4 x1 = *reinterpret_cast<const float4*>(xp + 4);
        float4 x2 = *reinterpret_cast<const float4*>(xp + 8);
        float4 x3 = *reinterpret_cast<const float4*>(xp + 12);
        xin[0]=x0.x; xin[1]=x0.y; xin[2]=x0.z; xin[3]=x0.w;
        xin[4]=x1.x; xin[5]=x1.y; xin[6]=x1.z; xin[7]=x1.w;
        xin[8]=x2.x; xin[9]=x2.y; xin[10]=x2.z; xin[11]=x2.w;
        xin[12]=x3.x; xin[13]=x3.y; xin[14]=x3.z; xin[15]=x3.w;
#pragma unroll
        for (int d = 0; d < 8; ++d) xin[16+d] = hv[d];

        float ap[8] = {0,0,0,0,0,0,0,0};
#pragma unroll
        for (int jj = 0; jj < 8; ++jj) {
            const int j = q + (jj << 3);
            float s1 = ls_pb1[j];
#pragma unroll
            for (int c4 = 0; c4 < 6; ++c4) {
                f32x4 wv = *reinterpret_cast<const f32x4*>(&ls_pW1T[j][c4*4]);
#pragma unroll
                for (int r = 0; r < 4; ++r) s1 += xin[c4*4+r] * wv[r];
            }
            s1 = fmaxf(s1, 0.f);
            f32x4 w2a = *reinterpret_cast<const f32x4*>(&ls_pW2[j][0]);
            f32x4 w2b = *reinterpret_cast<const f32x4*>(&ls_pW2[j][4]);
#pragma unroll
            for (int r = 0; r < 4; ++r) { ap[r] += s1*w2a[r]; ap[4+r] += s1*w2b[r]; }
        }
        float aps[8];
#pragma unroll
        for (int d = 0; d < 8; ++d) {
            float t = ap[d];
            t += __shfl_xor(t, 1); t += __shfl_xor(t, 2); t += __shfl_xor(t, 4);
            aps[d] = t;
        }
        float outp = hv[q] + aps[q] + ls_pb2[q];
        ls_hold[node][b*8 + q] = outp;
        ls_h8st[b*8 + q][node] = f2fp8(outp);
    }
    // pre-load z for substep 0 (latency hides under barrier)
    float4 zn0, zn1;
    {
        const size_t zb = ((size_t)b)*((size_t)NN*DD) + (size_t)(i0+node)*DD;
        zn0 = *reinterpret_cast<const float4*>(p.z_all + zb);
        zn1 = *reinterpret_cast<const float4*>(p.z_all + zb + 4);
    }
    __syncthreads();
    if (tid < 256) {    // pack 4 fp8 and store via L2-bypassing agent atomics
        int c = tid >> 2, n0 = (tid & 3) << 2;
        unsigned int v = *reinterpret_cast<const unsigned int*>(&ls_h8st[c][n0]);
        __hip_atomic_store(reinterpret_cast<unsigned int*>(
            p.h8 + (size_t)c*NN + i0 + n0), v,
            __ATOMIC_RELAXED, __HIP_MEMORY_SCOPE_AGENT);
    }
    gbar2(&p.cnt[0], tid);

    // ---- 60 substeps ----
    for (int g = 0; g < (SS-1)*KSUB; ++g) {
        const int s = g >> 2, k = g & 3;
        const unsigned char* hin  = p.h8 + (size_t)g * HSZ;
        unsigned char*       hout = p.h8 + (size_t)(g+1) * HSZ;

        const float t0 = ls_times[s], t1 = ls_times[s+1];
        const float dt = (t1 - t0) * 0.25f;
        const float tk = t0 + (float)k * dt;
        const float sqdt = sqrtf(dt);
        const bool dopert = (k == 3) && (s < SS - 2);

        // ---- GEMM: h_graph partials; wave = 256-wide K chunk, fp8 MFMA ----
        {
            const int wave = tid >> 6, lane = tid & 63;
            const int k0 = wave << 8;
            const int lrow = lane & 15;
            const int ksub = (lane >> 4) << 3;
            const int abase = lrow << 12;
            const int axor  = (lrow & 15) << 3;
            f32x4 acc[4];
#pragma unroll
            for (int ct = 0; ct < 4; ++ct) acc[ct] = (f32x4){0.f,0.f,0.f,0.f};
#pragma unroll
            for (int kk = 0; kk < 8; ++kk) {
                const int koff = k0 + kk*32 + ksub;
                long bfr = *reinterpret_cast<const long*>(&ls_A8[abase + (koff ^ axor)]);
#pragma unroll
                for (int ct = 0; ct < 4; ++ct) {
                    long av = *reinterpret_cast<const long*>(
                        hin + (size_t)(ct*16 + lrow)*NN + koff);
                    acc[ct] = __builtin_amdgcn_mfma_f32_16x16x32_fp8_fp8(
                        av, bfr, acc[ct], 0, 0, 0);
                }
            }
            const int rb = (lane >> 4) << 2;
            if (wave < 8) {
#pragma unroll
                for (int ct = 0; ct < 4; ++ct)
#pragma unroll
                    for (int r = 0; r < 4; ++r)
                        ls_part[wave][lrow][ct*16 + rb + r] = acc[ct][r];
            }
            __syncthreads();
            if (wave >= 8) {
#pragma unroll
                for (int ct = 0; ct < 4; ++ct)
#pragma unroll
                    for (int r = 0; r < 4; ++r)
                        ls_part[wave-8][lrow][ct*16 + rb + r] += acc[ct][r];
            }
            __syncthreads();
        }

        // ---- per-(b,node) MLPs: 8 threads/row ----
        float ing[9], inh[9];
        {
            f32x4 g0 = (f32x4){0,0,0,0}, g1 = (f32x4){0,0,0,0};
#pragma unroll
            for (int w = 0; w < 8; ++w) {
                g0 += *reinterpret_cast<const f32x4*>(&ls_part[w][node][b*8]);
                g1 += *reinterpret_cast<const f32x4*>(&ls_part[w][node][b*8+4]);
            }
            f32x4 h0v = *reinterpret_cast<const f32x4*>(&ls_hold[node][b*8]);
            f32x4 h1v = *reinterpret_cast<const f32x4*>(&ls_hold[node][b*8+4]);
#pragma unroll
            for (int r = 0; r < 4; ++r) {
                ing[r] = g0[r]*GSCALE; ing[4+r] = g1[r]*GSCALE;
                inh[r] = h0v[r];       inh[4+r] = h1v[r];
            }
        }
        ing[8] = tk; inh[8] = tk;
        float adr[8] = {0,0,0,0,0,0,0,0}, adf[8] = {0,0,0,0,0,0,0,0};
#pragma unroll
        for (int jj = 0; jj < 8; ++jj) {
            const int j = q + (jj << 3);
            f32x4 w1a = *reinterpret_cast<const f32x4*>(&ls_dW1T[j][0]);
            f32x4 w1b = *reinterpret_cast<const f32x4*>(&ls_dW1T[j][4]);
            float w1t = ls_dW1T[j][8];
            f32x4 v1a = *reinterpret_cast<const f32x4*>(&ls_fW1T[j][0]);
            f32x4 v1b = *reinterpret_cast<const f32x4*>(&ls_fW1T[j][4]);
            float v1t = ls_fW1T[j][8];
            float s1 = ls_db1[j], s2 = ls_fb1[j];
#pragma unroll
            for (int r = 0; r < 4; ++r) {
                s1 += ing[r]*w1a[r] + ing[4+r]*w1b[r];
                s2 += inh[r]*v1a[r] + inh[4+r]*v1b[r];
            }
            s1 += ing[8]*w1t; s2 += inh[8]*v1t;
            float th = ftanh(s1), sg = fsig(s2);
            f32x4 w2a = *reinterpret_cast<const f32x4*>(&ls_dW2[j][0]);
            f32x4 w2b = *reinterpret_cast<const f32x4*>(&ls_dW2[j][4]);
            f32x4 v2a = *reinterpret_cast<const f32x4*>(&ls_fW2[j][0]);
            f32x4 v2b = *reinterpret_cast<const f32x4*>(&ls_fW2[j][4]);
#pragma unroll
            for (int r = 0; r < 4; ++r) {
                adr[r] += th*w2a[r]; adr[4+r] += th*w2b[r];
                adf[r] += sg*v2a[r]; adf[4+r] += sg*v2b[r];
            }
        }
#pragma unroll
        for (int d = 0; d < 8; ++d) {
            adr[d] += __shfl_xor(adr[d], 1); adr[d] += __shfl_xor(adr[d], 2); adr[d] += __shfl_xor(adr[d], 4);
            adf[d] += __shfl_xor(adf[d], 1); adf[d] += __shfl_xor(adf[d], 2); adf[d] += __shfl_xor(adf[d], 4);
        }
        float zz[8] = {zn0.x, zn0.y, zn0.z, zn0.w, zn1.x, zn1.y, zn1.z, zn1.w};
        float hnew[8];
#pragma unroll
        for (int d = 0; d < 8; ++d) {
            float dr  = adr[d] + ls_db2[d];
            float dif = 0.1f * fsig(adf[d] + ls_fb2[d]);
            hnew[d] = inh[d] + dr * dt + dif * (sqdt * zz[d]);
        }

        if (k == 3) {
            p.traj[((size_t)((s+1)*BB + b))*((size_t)NN*DD) + (size_t)(i0+node)*DD + q] = hnew[q];
        }
        float outv;
        if (dopert) {
            float xin[24];
            const float* xp = p.x_all + ((size_t)(s+1)*BB + b)*((size_t)NN*IND) + (size_t)(i0+node)*IND;
            float4 x0 = *reinterpret_cast<const float4*>(xp);
            float4 x1 = *reinterpret_cast<const float4*>(xp + 4);
            float4 x2 = *reinterpret_cast<const float4*>(xp + 8);
            float4 x3 = *reinterpret_cast<const float4*>(xp + 12);
            xin[0]=x0.x; xin[1]=x0.y; xin[2]=x0.z; xin[3]=x0.w;
            xin[4]=x1.x; xin[5]=x1.y; xin[6]=x1.z; xin[7]=x1.w;
            xin[8]=x2.x; xin[9]=x2.y; xin[10]=x2.z; xin[11]=x2.w;
            xin[12]=x3.x; xin[13]=x3.y; xin[14]=x3.z; xin[15]=x3.w;
#pragma unroll
            for (int d = 0; d < 8; ++d) xin[16+d] = hnew[d];
            float ap[8] = {0,0,0,0,0,0,0,0};
#pragma unroll
            for (int jj = 0; jj < 8; ++jj) {
                const int j = q + (jj << 3);
                float s1 = ls_pb1[j];
#pragma unroll
                for (int c4 = 0; c4 < 6; ++c4) {
                    f32x4 wv = *reinterpret_cast<const f32x4*>(&ls_pW1T[j][c4*4]);
#pragma unroll
                    for (int r = 0; r < 4; ++r) s1 += xin[c4*4+r] * wv[r];
                }
                s1 = fmaxf(s1, 0.f);
                f32x4 w2a = *reinterpret_cast<const f32x4*>(&ls_pW2[j][0]);
                f32x4 w2b = *reinterpret_cast<const f32x4*>(&ls_pW2[j][4]);
#pragma unroll
                for (int r = 0; r < 4; ++r) { ap[r] += s1*w2a[r]; ap[4+r] += s1*w2b[r]; }
            }
            float aps[8];
#pragma unroll
            for (int d = 0; d < 8; ++d) {
                float t = ap[d];
                t += __shfl_xor(t, 1); t += __shfl_xor(t, 2); t += __shfl_xor(t, 4);
                aps[d] = t;
            }
            outv = hnew[q] + aps[q] + ls_pb2[q];
        } else {
            outv = hnew[q];
        }
        ls_hold[node][b*8 + q] = outv;
        ls_h8st[b*8 + q][node] = f2fp8(outv);

        // prefetch z for next substep (completes under the barrier)
        if (g + 1 < (SS-1)*KSUB) {
            const size_t zb = ((size_t)((g+1)*BB + b))*((size_t)NN*DD) + (size_t)(i0+node)*DD;
            zn0 = *reinterpret_cast<const float4*>(p.z_all + zb);
            zn1 = *reinterpret_cast<const float4*>(p.z_all + zb + 4);
        }
        __syncthreads();
        if (tid < 256) {
            int c = tid >> 2, n0 = (tid & 3) << 2;
            unsigned int v = *reinterpret_cast<const unsigned int*>(&ls_h8st[c][n0]);
            __hip_atomic_store(reinterpret_cast<unsigned int*>(
                hout + (size_t)c*NN + i0 + n0), v,
                __ATOMIC_RELAXED, __HIP_MEMORY_SCOPE_AGENT);
        }
        if (g < (SS-1)*KSUB - 1) gbar2(&p.cnt[g+1], tid);
    }
}

// ---------------------------------------------------------------------------
// readout: relu(traj @ rW1 + rb1) @ rW2 + rb2 ; 2 threads/row (16 outs each)
// ---------------------------------------------------------------------------
__global__ __launch_bounds__(256) void k_readout(
    const float* __restrict__ traj,
    const float* __restrict__ rW1, const float* __restrict__ rb1,
    const float* __restrict__ rW2, const float* __restrict__ rb2,
    float* __restrict__ outr)
{
    __shared__ float ls_W1T[64][12];
    __shared__ float ls_W2[64][32];
    __shared__ float ls_b1[64];    __shared__ float ls_b2[32];
    const int tid = threadIdx.x;
    for (int idx = tid; idx < 8*64;  idx += 256) ls_W1T[idx&63][idx>>6] = rW1[idx];
    for (int idx = tid; idx < 64*32; idx += 256) ls_W2[idx>>5][idx&31] = rW2[idx];
    if (tid < 64) ls_b1[tid] = rb1[tid];
    else if (tid < 96) ls_b2[tid-64] = rb2[tid-64];
    __syncthreads();

    const int half = tid & 1, ob = half << 4;
    const size_t row = (size_t)blockIdx.x * 128 + (tid >> 1);
    const float4* pi = reinterpret_cast<const float4*>(traj + row*8);
    float4 a0 = pi[0], a1 = pi[1];
    float in[8] = {a0.x,a0.y,a0.z,a0.w,a1.x,a1.y,a1.z,a1.w};
    float out[16];
#pragma unroll
    for (int o4 = 0; o4 < 4; ++o4) {
        f32x4 bv = *reinterpret_cast<const f32x4*>(&ls_b2[ob + o4*4]);
#pragma unroll
        for (int r = 0; r < 4; ++r) out[o4*4+r] = bv[r];
    }
    for (int j = 0; j < 64; ++j) {
        f32x4 w1a = *reinterpret_cast<const f32x4*>(&ls_W1T[j][0]);
        f32x4 w1b = *reinterpret_cast<const f32x4*>(&ls_W1T[j][4]);
        float s1 = ls_b1[j];
#pragma unroll
        for (int r = 0; r < 4; ++r) s1 += in[r]*w1a[r] + in[4+r]*w1b[r];
        s1 = fmaxf(s1, 0.f);
#pragma unroll
        for (int o4 = 0; o4 < 4; ++o4) {
            f32x4 w2 = *reinterpret_cast<const f32x4*>(&ls_W2[j][ob + o4*4]);
#pragma unroll
            for (int r = 0; r < 4; ++r) out[o4*4+r] += s1 * w2[r];
        }
    }
    float* op = outr + row*32 + ob;
#pragma unroll
    for (int o4 = 0; o4 < 4; ++o4) {
        float4 v = {out[o4*4], out[o4*4+1], out[o4*4+2], out[o4*4+3]};
        *reinterpret_cast<float4*>(op + o4*4) = v;
    }
}

// ---------------------------------------------------------------------------
extern "C" void kernel_launch(void* const* d_in, const int* in_sizes, int n_in,
                              void* d_out, int out_size, void* d_ws, size_t ws_size,
                              hipStream_t stream) {
    (void)in_sizes; (void)n_in; (void)out_size; (void)ws_size;
    const float* times = (const float*)d_in[0];
    const float* x_all = (const float*)d_in[1];
    const float* h0    = (const float*)d_in[2];
    const float* Amat  = (const float*)d_in[3];
    const float* z_all = (const float*)d_in[4];
    const float* dW1 = (const float*)d_in[5],  *db1 = (const float*)d_in[6];
    const float* dW2 = (const float*)d_in[7],  *db2 = (const float*)d_in[8];
    const float* fW1 = (const float*)d_in[9],  *fb1 = (const float*)d_in[10];
    const float* fW2 = (const float*)d_in[11], *fb2 = (const float*)d_in[12];
    const float* pW1 = (const float*)d_in[13], *pb1 = (const float*)d_in[14];
    const float* pW2 = (const float*)d_in[15], *pb2 = (const float*)d_in[16];
    const float* rW1 = (const float*)d_in[17], *rb1 = (const float*)d_in[18];
    const float* rW2 = (const float*)d_in[19], *rb2 = (const float*)d_in[20];

    float* traj = (float*)d_out;                      // [16,8,4096,8]
    float* outr = traj + (size_t)SS*BB*NN*DD;         // [16,8,4096,32]

    char* ws = (char*)d_ws;
    unsigned char* A8  = (unsigned char*)ws;                 // 16 MB
    unsigned char* h8  = (unsigned char*)(ws + (16u << 20)); // 61 x 256 KB
    unsigned int*  cnt = (unsigned int*)(ws + (35u << 20));  // 64 counters

    k_convA8<<<NN*NN/(256*8), 256, 0, stream>>>(Amat, A8, cnt);

    PArgs pa;
    pa.A8 = A8; pa.times = times; pa.x_all = x_all; pa.z_all = z_all; pa.h0 = h0;
    pa.dW1 = dW1; pa.db1 = db1; pa.dW2 = dW2; pa.db2 = db2;
    pa.fW1 = fW1; pa.fb1 = fb1; pa.fW2 = fW2; pa.fb2 = fb2;
    pa.pW1 = pW1; pa.pb1 = pb1; pa.pW2 = pW2; pa.pb2 = pb2;
    pa.traj = traj; pa.h8 = h8; pa.cnt = cnt;
    k_persist<<<NWG, TPB, 0, stream>>>(pa);

    k_readout<<<(SS*BB*NN)/128, 256, 0, stream>>>(traj, rW1, rb1, rW2, rb2, outr);
}

// Round 8
// 1741.618 us; speedup vs baseline: 2.0937x; 1.2149x over previous
//
#include <hip/hip_runtime.h>
#include <hip/hip_fp8.h>
#include <math.h>

typedef __attribute__((ext_vector_type(4))) float f32x4;

#define NN   4096
#define BB   8
#define DD   8
#define SS   16
#define KSUB 4
#define IND  16
#define NWG  256
#define TPB  1024
#define HSZ  (64 * 4096)           // one rotating h buffer (fp8), 256 KB
#define GSCALE 1.52587890625e-5f   // 2^-16 (A stored as fp8 of A*2^16)

__device__ __forceinline__ float fsig(float x) {
    return __builtin_amdgcn_rcpf(1.f + __expf(-x));
}
__device__ __forceinline__ float ftanh(float x) {
    x = fminf(fmaxf(x, -15.f), 15.f);
    float e = __expf(2.f * x);
    return (e - 1.f) * __builtin_amdgcn_rcpf(e + 1.f);
}
__device__ __forceinline__ unsigned char f2fp8(float x) {
    return __hip_cvt_float_to_fp8(x, __HIP_SATFINITE, __HIP_E4M3);
}

// ---------------------------------------------------------------------------
// A (fp32) -> A8 (fp8 e4m3 of A*65536), and zero the barrier region (2048 u32)
// ---------------------------------------------------------------------------
__global__ __launch_bounds__(256) void k_convA8(const float* __restrict__ A,
                                                unsigned char* __restrict__ A8,
                                                unsigned int* __restrict__ cnt) {
    if (blockIdx.x == 0)
        for (int idx = threadIdx.x; idx < 2048; idx += 256) cnt[idx] = 0u;
    size_t i = ((size_t)blockIdx.x * 256 + threadIdx.x) * 8;
    float4 v0 = *reinterpret_cast<const float4*>(A + i);
    float4 v1 = *reinterpret_cast<const float4*>(A + i + 4);
    unsigned char o[8];
    o[0] = f2fp8(v0.x * 65536.f); o[1] = f2fp8(v0.y * 65536.f);
    o[2] = f2fp8(v0.z * 65536.f); o[3] = f2fp8(v0.w * 65536.f);
    o[4] = f2fp8(v1.x * 65536.f); o[5] = f2fp8(v1.y * 65536.f);
    o[6] = f2fp8(v1.z * 65536.f); o[7] = f2fp8(v1.w * 65536.f);
    *reinterpret_cast<unsigned long long*>(&A8[i]) =
        *reinterpret_cast<const unsigned long long*>(o);
}

// ---------------------------------------------------------------------------
// Hierarchical grid barrier (no L2 writeback, no single-line contention):
//  - arrivals: 8 spread counters (one 128B line each), monotonic (no reset)
//  - combiner: wg0/tid0 is the ONLY reader of the counters; releases by
//    writing the epoch to 8 per-group mirror lines
//  - waiters: poll only their group's mirror (<=32 WGs per line)
// h-state crossed XCDs via agent-scope atomic stores before this; every wave
// drains vmcnt before arriving. Post-barrier h reads are plain cached loads
// of write-once addresses.
// ---------------------------------------------------------------------------
__device__ __forceinline__ void gbar3(unsigned int* cnt, int wg, int tid,
                                      unsigned int epoch) {
    unsigned int* ep = cnt + 1024;           // mirrors live 4 KB above counters
    asm volatile("s_waitcnt vmcnt(0)" ::: "memory");
    __syncthreads();
    if (wg == 0) {
        if (tid == 0) {
            __hip_atomic_fetch_add(&cnt[0], 1u, __ATOMIC_RELAXED, __HIP_MEMORY_SCOPE_AGENT);
            for (;;) {
                unsigned int s = 0;
#pragma unroll
                for (int i = 0; i < 8; ++i)
                    s += __hip_atomic_load(&cnt[i * 32], __ATOMIC_RELAXED, __HIP_MEMORY_SCOPE_AGENT);
                if (s >= (unsigned int)NWG * epoch) break;
                __builtin_amdgcn_s_sleep(1);
            }
#pragma unroll
            for (int i = 0; i < 8; ++i)
                __hip_atomic_store(&ep[i * 32], epoch, __ATOMIC_RELAXED, __HIP_MEMORY_SCOPE_AGENT);
        }
    } else if (tid == 0) {
        __hip_atomic_fetch_add(&cnt[(wg & 7) * 32], 1u, __ATOMIC_RELAXED, __HIP_MEMORY_SCOPE_AGENT);
        while (__hip_atomic_load(&ep[(wg & 7) * 32], __ATOMIC_RELAXED, __HIP_MEMORY_SCOPE_AGENT) < epoch)
            __builtin_amdgcn_s_sleep(2);
    }
    __syncthreads();
    asm volatile("" ::: "memory");
}

// ---------------------------------------------------------------------------
// Persistent kernel: prep + 60 substeps. 256 WGs x 1024 thr (1 WG/CU).
// ---------------------------------------------------------------------------
struct PArgs {
    const unsigned char* A8;
    const float *times, *x_all, *z_all, *h0;
    const float *dW1, *db1, *dW2, *db2;
    const float *fW1, *fb1, *fW2, *fb2;
    const float *pW1, *pb1, *pW2, *pb2;
    float* traj;
    unsigned char* h8;       // 61 rotating buffers of HSZ
    unsigned int* cnt;
};

__global__ __launch_bounds__(TPB, 4) void k_persist(PArgs p) {
    __shared__ __align__(16) unsigned char ls_A8[16 * 4096];   // 64 KB, swizzled
    __shared__ float ls_part[8][16][68];    // 34.8 KB
    __shared__ float ls_hold[16][68];       // persistent h tile (fp32)
    __shared__ __align__(4) unsigned char ls_h8st[64][16];     // packed h8 staging
    __shared__ float ls_dW1T[64][12]; __shared__ float ls_fW1T[64][12];
    __shared__ float ls_dW2[64][8];   __shared__ float ls_fW2[64][8];
    __shared__ float ls_pW1T[64][24]; __shared__ float ls_pW2[64][8];
    __shared__ float ls_db1[64];  __shared__ float ls_fb1[64];  __shared__ float ls_pb1[64];
    __shared__ float ls_db2[8];   __shared__ float ls_fb2[8];   __shared__ float ls_pb2[8];
    __shared__ float ls_times[SS];

    const int tid = threadIdx.x;
    const int wg  = blockIdx.x;
    const int i0  = (((wg & 7) << 5) | (wg >> 3)) << 4;   // XCD-contiguous 16-node tile

    // ---- stage weights (once) ----
    for (int idx = tid; idx < 9*64; idx += TPB) {
        int d = idx >> 6, j = idx & 63;
        ls_dW1T[j][d] = p.dW1[idx]; ls_fW1T[j][d] = p.fW1[idx];
    }
    for (int idx = tid; idx < 64*8; idx += TPB) {
        ls_dW2[idx>>3][idx&7] = p.dW2[idx]; ls_fW2[idx>>3][idx&7] = p.fW2[idx];
        ls_pW2[idx>>3][idx&7] = p.pW2[idx];
    }
    for (int idx = tid; idx < 24*64; idx += TPB) ls_pW1T[idx&63][idx>>6] = p.pW1[idx];
    if (tid < 64) { ls_db1[tid] = p.db1[tid]; ls_fb1[tid] = p.fb1[tid]; ls_pb1[tid] = p.pb1[tid]; }
    else if (tid < 72) { ls_db2[tid-64] = p.db2[tid-64]; ls_fb2[tid-64] = p.fb2[tid-64]; ls_pb2[tid-64] = p.pb2[tid-64]; }
    else if (tid >= 128 && tid < 128 + SS) ls_times[tid-128] = p.times[tid-128];

    // ---- stage A rows into LDS (once), XOR-swizzled ----
    for (int it = 0; it < 8; ++it) {
        int gi = (it * TPB + tid) * 8;          // byte index within 16x4096
        int node = gi >> 12, k = gi & 4095;
        unsigned long long v = *reinterpret_cast<const unsigned long long*>(
            p.A8 + (size_t)(i0 + node) * NN + k);
        *reinterpret_cast<unsigned long long*>(
            &ls_A8[(node << 12) + (k ^ ((node & 15) << 3))]) = v;
    }
    __syncthreads();

    const int q = tid & 7, row = tid >> 3;   // 128 rows, 8 threads each
    const int node = row & 15, b = row >> 4;

    // ---- prep: traj[0] = h0 ; hold = h0 + pert(x[0], h0) -> h8[0] ----
    {
        const float* hp = p.h0 + ((size_t)b * NN + i0 + node) * DD;
        float4 h0a = *reinterpret_cast<const float4*>(hp);
        float4 h0b = *reinterpret_cast<const float4*>(hp + 4);
        float hv[8] = {h0a.x,h0a.y,h0a.z,h0a.w,h0b.x,h0b.y,h0b.z,h0b.w};
        p.traj[((size_t)b * NN + i0 + node) * DD + q] = hv[q];

        float xin[24];
        const float* xp = p.x_all + ((size_t)b * NN + i0 + node) * IND;  // s=0
        float4 x0 = *reinterpret_cast<const float4*>(xp);
        float4 x1 = *reinterpret_cast<const float4*>(xp + 4);
        float4 x2 = *reinterpret_cast<const float4*>(xp + 8);
        float4 x3 = *reinterpret_cast<const float4*>(xp + 12);
        xin[0]=x0.x; xin[1]=x0.y; xin[2]=x0.z; xin[3]=x0.w;
        xin[4]=x1.x; xin[5]=x1.y; xin[6]=x1.z; xin[7]=x1.w;
        xin[8]=x2.x; xin[9]=x2.y; xin[10]=x2.z; xin[11]=x2.w;
        xin[12]=x3.x; xin[13]=x3.y; xin[14]=x3.z; xin[15]=x3.w;
#pragma unroll
        for (int d = 0; d < 8; ++d) xin[16+d] = hv[d];

        float ap[8] = {0,0,0,0,0,0,0,0};
#pragma unroll
        for (int jj = 0; jj < 8; ++jj) {
            const int j = q + (jj << 3);
            float s1 = ls_pb1[j];
#pragma unroll
            for (int c4 = 0; c4 < 6; ++c4) {
                f32x4 wv = *reinterpret_cast<const f32x4*>(&ls_pW1T[j][c4*4]);
#pragma unroll
                for (int r = 0; r < 4; ++r) s1 += xin[c4*4+r] * wv[r];
            }
            s1 = fmaxf(s1, 0.f);
            f32x4 w2a = *reinterpret_cast<const f32x4*>(&ls_pW2[j][0]);
            f32x4 w2b = *reinterpret_cast<const f32x4*>(&ls_pW2[j][4]);
#pragma unroll
            for (int r = 0; r < 4; ++r) { ap[r] += s1*w2a[r]; ap[4+r] += s1*w2b[r]; }
        }
        float aps[8];
#pragma unroll
        for (int d = 0; d < 8; ++d) {
            float t = ap[d];
            t += __shfl_xor(t, 1); t += __shfl_xor(t, 2); t += __shfl_xor(t, 4);
            aps[d] = t;
        }
        float outp = hv[q] + aps[q] + ls_pb2[q];
        ls_hold[node][b*8 + q] = outp;
        ls_h8st[b*8 + q][node] = f2fp8(outp);
    }
    // pre-load z for substep 0 (latency hides under barrier)
    float4 zn0, zn1;
    {
        const size_t zb = ((size_t)b)*((size_t)NN*DD) + (size_t)(i0+node)*DD;
        zn0 = *reinterpret_cast<const float4*>(p.z_all + zb);
        zn1 = *reinterpret_cast<const float4*>(p.z_all + zb + 4);
    }
    __syncthreads();
    if (tid < 256) {    // pack 4 fp8 and store via L2-bypassing agent atomics
        int c = tid >> 2, n0 = (tid & 3) << 2;
        unsigned int v = *reinterpret_cast<const unsigned int*>(&ls_h8st[c][n0]);
        __hip_atomic_store(reinterpret_cast<unsigned int*>(
            p.h8 + (size_t)c*NN + i0 + n0), v,
            __ATOMIC_RELAXED, __HIP_MEMORY_SCOPE_AGENT);
    }
    gbar3(p.cnt, wg, tid, 1u);

    // ---- 60 substeps ----
    for (int g = 0; g < (SS-1)*KSUB; ++g) {
        const int s = g >> 2, k = g & 3;
        const unsigned char* hin  = p.h8 + (size_t)g * HSZ;
        unsigned char*       hout = p.h8 + (size_t)(g+1) * HSZ;

        const float t0 = ls_times[s], t1 = ls_times[s+1];
        const float dt = (t1 - t0) * 0.25f;
        const float tk = t0 + (float)k * dt;
        const float sqdt = sqrtf(dt);
        const bool dopert = (k == 3) && (s < SS - 2);

        // ---- GEMM: h_graph partials; wave = 256-wide K chunk, fp8 MFMA ----
        {
            const int wave = tid >> 6, lane = tid & 63;
            const int k0 = wave << 8;
            const int lrow = lane & 15;
            const int ksub = (lane >> 4) << 3;
            const int abase = lrow << 12;
            const int axor  = (lrow & 15) << 3;
            f32x4 acc[4];
#pragma unroll
            for (int ct = 0; ct < 4; ++ct) acc[ct] = (f32x4){0.f,0.f,0.f,0.f};
#pragma unroll
            for (int kk = 0; kk < 8; ++kk) {
                const int koff = k0 + kk*32 + ksub;
                long bfr = *reinterpret_cast<const long*>(&ls_A8[abase + (koff ^ axor)]);
#pragma unroll
                for (int ct = 0; ct < 4; ++ct) {
                    long av = *reinterpret_cast<const long*>(
                        hin + (size_t)(ct*16 + lrow)*NN + koff);
                    acc[ct] = __builtin_amdgcn_mfma_f32_16x16x32_fp8_fp8(
                        av, bfr, acc[ct], 0, 0, 0);
                }
            }
            const int rb = (lane >> 4) << 2;
            if (wave < 8) {
#pragma unroll
                for (int ct = 0; ct < 4; ++ct)
#pragma unroll
                    for (int r = 0; r < 4; ++r)
                        ls_part[wave][lrow][ct*16 + rb + r] = acc[ct][r];
            }
            __syncthreads();
            if (wave >= 8) {
#pragma unroll
                for (int ct = 0; ct < 4; ++ct)
#pragma unroll
                    for (int r = 0; r < 4; ++r)
                        ls_part[wave-8][lrow][ct*16 + rb + r] += acc[ct][r];
            }
            __syncthreads();
        }

        // ---- per-(b,node) MLPs: 8 threads/row ----
        float ing[9], inh[9];
        {
            f32x4 g0 = (f32x4){0,0,0,0}, g1 = (f32x4){0,0,0,0};
#pragma unroll
            for (int w = 0; w < 8; ++w) {
                g0 += *reinterpret_cast<const f32x4*>(&ls_part[w][node][b*8]);
                g1 += *reinterpret_cast<const f32x4*>(&ls_part[w][node][b*8+4]);
            }
            f32x4 h0v = *reinterpret_cast<const f32x4*>(&ls_hold[node][b*8]);
            f32x4 h1v = *reinterpret_cast<const f32x4*>(&ls_hold[node][b*8+4]);
#pragma unroll
            for (int r = 0; r < 4; ++r) {
                ing[r] = g0[r]*GSCALE; ing[4+r] = g1[r]*GSCALE;
                inh[r] = h0v[r];       inh[4+r] = h1v[r];
            }
        }
        ing[8] = tk; inh[8] = tk;
        float adr[8] = {0,0,0,0,0,0,0,0}, adf[8] = {0,0,0,0,0,0,0,0};
#pragma unroll
        for (int jj = 0; jj < 8; ++jj) {
            const int j = q + (jj << 3);
            f32x4 w1a = *reinterpret_cast<const f32x4*>(&ls_dW1T[j][0]);
            f32x4 w1b = *reinterpret_cast<const f32x4*>(&ls_dW1T[j][4]);
            float w1t = ls_dW1T[j][8];
            f32x4 v1a = *reinterpret_cast<const f32x4*>(&ls_fW1T[j][0]);
            f32x4 v1b = *reinterpret_cast<const f32x4*>(&ls_fW1T[j][4]);
            float v1t = ls_fW1T[j][8];
            float s1 = ls_db1[j], s2 = ls_fb1[j];
#pragma unroll
            for (int r = 0; r < 4; ++r) {
                s1 += ing[r]*w1a[r] + ing[4+r]*w1b[r];
                s2 += inh[r]*v1a[r] + inh[4+r]*v1b[r];
            }
            s1 += ing[8]*w1t; s2 += inh[8]*v1t;
            float th = ftanh(s1), sg = fsig(s2);
            f32x4 w2a = *reinterpret_cast<const f32x4*>(&ls_dW2[j][0]);
            f32x4 w2b = *reinterpret_cast<const f32x4*>(&ls_dW2[j][4]);
            f32x4 v2a = *reinterpret_cast<const f32x4*>(&ls_fW2[j][0]);
            f32x4 v2b = *reinterpret_cast<const f32x4*>(&ls_fW2[j][4]);
#pragma unroll
            for (int r = 0; r < 4; ++r) {
                adr[r] += th*w2a[r]; adr[4+r] += th*w2b[r];
                adf[r] += sg*v2a[r]; adf[4+r] += sg*v2b[r];
            }
        }
#pragma unroll
        for (int d = 0; d < 8; ++d) {
            adr[d] += __shfl_xor(adr[d], 1); adr[d] += __shfl_xor(adr[d], 2); adr[d] += __shfl_xor(adr[d], 4);
            adf[d] += __shfl_xor(adf[d], 1); adf[d] += __shfl_xor(adf[d], 2); adf[d] += __shfl_xor(adf[d], 4);
        }
        float zz[8] = {zn0.x, zn0.y, zn0.z, zn0.w, zn1.x, zn1.y, zn1.z, zn1.w};
        float hnew[8];
#pragma unroll
        for (int d = 0; d < 8; ++d) {
            float dr  = adr[d] + ls_db2[d];
            float dif = 0.1f * fsig(adf[d] + ls_fb2[d]);
            hnew[d] = inh[d] + dr * dt + dif * (sqdt * zz[d]);
        }

        if (k == 3) {
            p.traj[((size_t)((s+1)*BB + b))*((size_t)NN*DD) + (size_t)(i0+node)*DD + q] = hnew[q];
        }
        float outv;
        if (dopert) {
            float xin[24];
            const float* xp = p.x_all + ((size_t)(s+1)*BB + b)*((size_t)NN*IND) + (size_t)(i0+node)*IND;
            float4 x0 = *reinterpret_cast<const float4*>(xp);
            float4 x1 = *reinterpret_cast<const float4*>(xp + 4);
            float4 x2 = *reinterpret_cast<const float4*>(xp + 8);
            float4 x3 = *reinterpret_cast<const float4*>(xp + 12);
            xin[0]=x0.x; xin[1]=x0.y; xin[2]=x0.z; xin[3]=x0.w;
            xin[4]=x1.x; xin[5]=x1.y; xin[6]=x1.z; xin[7]=x1.w;
            xin[8]=x2.x; xin[9]=x2.y; xin[10]=x2.z; xin[11]=x2.w;
            xin[12]=x3.x; xin[13]=x3.y; xin[14]=x3.z; xin[15]=x3.w;
#pragma unroll
            for (int d = 0; d < 8; ++d) xin[16+d] = hnew[d];
            float ap[8] = {0,0,0,0,0,0,0,0};
#pragma unroll
            for (int jj = 0; jj < 8; ++jj) {
                const int j = q + (jj << 3);
                float s1 = ls_pb1[j];
#pragma unroll
                for (int c4 = 0; c4 < 6; ++c4) {
                    f32x4 wv = *reinterpret_cast<const f32x4*>(&ls_pW1T[j][c4*4]);
#pragma unroll
                    for (int r = 0; r < 4; ++r) s1 += xin[c4*4+r] * wv[r];
                }
                s1 = fmaxf(s1, 0.f);
                f32x4 w2a = *reinterpret_cast<const f32x4*>(&ls_pW2[j][0]);
                f32x4 w2b = *reinterpret_cast<const f32x4*>(&ls_pW2[j][4]);
#pragma unroll
                for (int r = 0; r < 4; ++r) { ap[r] += s1*w2a[r]; ap[4+r] += s1*w2b[r]; }
            }
            float aps[8];
#pragma unroll
            for (int d = 0; d < 8; ++d) {
                float t = ap[d];
                t += __shfl_xor(t, 1); t += __shfl_xor(t, 2); t += __shfl_xor(t, 4);
                aps[d] = t;
            }
            outv = hnew[q] + aps[q] + ls_pb2[q];
        } else {
            outv = hnew[q];
        }
        ls_hold[node][b*8 + q] = outv;
        ls_h8st[b*8 + q][node] = f2fp8(outv);

        // prefetch z for next substep (completes under the barrier)
        if (g + 1 < (SS-1)*KSUB) {
            const size_t zb = ((size_t)((g+1)*BB + b))*((size_t)NN*DD) + (size_t)(i0+node)*DD;
            zn0 = *reinterpret_cast<const float4*>(p.z_all + zb);
            zn1 = *reinterpret_cast<const float4*>(p.z_all + zb + 4);
        }
        __syncthreads();
        if (tid < 256) {
            int c = tid >> 2, n0 = (tid & 3) << 2;
            unsigned int v = *reinterpret_cast<const unsigned int*>(&ls_h8st[c][n0]);
            __hip_atomic_store(reinterpret_cast<unsigned int*>(
                hout + (size_t)c*NN + i0 + n0), v,
                __ATOMIC_RELAXED, __HIP_MEMORY_SCOPE_AGENT);
        }
        if (g < (SS-1)*KSUB - 1) gbar3(p.cnt, wg, tid, (unsigned int)(g + 2));
    }
}

// ---------------------------------------------------------------------------
// readout: relu(traj @ rW1 + rb1) @ rW2 + rb2 ; 2 threads/row (16 outs each)
// ---------------------------------------------------------------------------
__global__ __launch_bounds__(256) void k_readout(
    const float* __restrict__ traj,
    const float* __restrict__ rW1, const float* __restrict__ rb1,
    const float* __restrict__ rW2, const float* __restrict__ rb2,
    float* __restrict__ outr)
{
    __shared__ float ls_W1T[64][12];
    __shared__ float ls_W2[64][32];
    __shared__ float ls_b1[64];    __shared__ float ls_b2[32];
    const int tid = threadIdx.x;
    for (int idx = tid; idx < 8*64;  idx += 256) ls_W1T[idx&63][idx>>6] = rW1[idx];
    for (int idx = tid; idx < 64*32; idx += 256) ls_W2[idx>>5][idx&31] = rW2[idx];
    if (tid < 64) ls_b1[tid] = rb1[tid];
    else if (tid < 96) ls_b2[tid-64] = rb2[tid-64];
    __syncthreads();

    const int half = tid & 1, ob = half << 4;
    const size_t row = (size_t)blockIdx.x * 128 + (tid >> 1);
    const float4* pi = reinterpret_cast<const float4*>(traj + row*8);
    float4 a0 = pi[0], a1 = pi[1];
    float in[8] = {a0.x,a0.y,a0.z,a0.w,a1.x,a1.y,a1.z,a1.w};
    float out[16];
#pragma unroll
    for (int o4 = 0; o4 < 4; ++o4) {
        f32x4 bv = *reinterpret_cast<const f32x4*>(&ls_b2[ob + o4*4]);
#pragma unroll
        for (int r = 0; r < 4; ++r) out[o4*4+r] = bv[r];
    }
    for (int j = 0; j < 64; ++j) {
        f32x4 w1a = *reinterpret_cast<const f32x4*>(&ls_W1T[j][0]);
        f32x4 w1b = *reinterpret_cast<const f32x4*>(&ls_W1T[j][4]);
        float s1 = ls_b1[j];
#pragma unroll
        for (int r = 0; r < 4; ++r) s1 += in[r]*w1a[r] + in[4+r]*w1b[r];
        s1 = fmaxf(s1, 0.f);
#pragma unroll
        for (int o4 = 0; o4 < 4; ++o4) {
            f32x4 w2 = *reinterpret_cast<const f32x4*>(&ls_W2[j][ob + o4*4]);
#pragma unroll
            for (int r = 0; r < 4; ++r) out[o4*4+r] += s1 * w2[r];
        }
    }
    float* op = outr + row*32 + ob;
#pragma unroll
    for (int o4 = 0; o4 < 4; ++o4) {
        float4 v = {out[o4*4], out[o4*4+1], out[o4*4+2], out[o4*4+3]};
        *reinterpret_cast<float4*>(op + o4*4) = v;
    }
}

// ---------------------------------------------------------------------------
extern "C" void kernel_launch(void* const* d_in, const int* in_sizes, int n_in,
                              void* d_out, int out_size, void* d_ws, size_t ws_size,
                              hipStream_t stream) {
    (void)in_sizes; (void)n_in; (void)out_size; (void)ws_size;
    const float* times = (const float*)d_in[0];
    const float* x_all = (const float*)d_in[1];
    const float* h0    = (const float*)d_in[2];
    const float* Amat  = (const float*)d_in[3];
    const float* z_all = (const float*)d_in[4];
    const float* dW1 = (const float*)d_in[5],  *db1 = (const float*)d_in[6];
    const float* dW2 = (const float*)d_in[7],  *db2 = (const float*)d_in[8];
    const float* fW1 = (const float*)d_in[9],  *fb1 = (const float*)d_in[10];
    const float* fW2 = (const float*)d_in[11], *fb2 = (const float*)d_in[12];
    const float* pW1 = (const float*)d_in[13], *pb1 = (const float*)d_in[14];
    const float* pW2 = (const float*)d_in[15], *pb2 = (const float*)d_in[16];
    const float* rW1 = (const float*)d_in[17], *rb1 = (const float*)d_in[18];
    const float* rW2 = (const float*)d_in[19], *rb2 = (const float*)d_in[20];

    float* traj = (float*)d_out;                      // [16,8,4096,8]
    float* outr = traj + (size_t)SS*BB*NN*DD;         // [16,8,4096,32]

    char* ws = (char*)d_ws;
    unsigned char* A8  = (unsigned char*)ws;                 // 16 MB
    unsigned char* h8  = (unsigned char*)(ws + (16u << 20)); // 61 x 256 KB
    unsigned int*  cnt = (unsigned int*)(ws + (35u << 20));  // counters+mirrors (8 KB)

    k_convA8<<<NN*NN/(256*8), 256, 0, stream>>>(Amat, A8, cnt);

    PArgs pa;
    pa.A8 = A8; pa.times = times; pa.x_all = x_all; pa.z_all = z_all; pa.h0 = h0;
    pa.dW1 = dW1; pa.db1 = db1; pa.dW2 = dW2; pa.db2 = db2;
    pa.fW1 = fW1; pa.fb1 = fb1; pa.fW2 = fW2; pa.fb2 = fb2;
    pa.pW1 = pW1; pa.pb1 = pb1; pa.pW2 = pW2; pa.pb2 = pb2;
    pa.traj = traj; pa.h8 = h8; pa.cnt = cnt;
    k_persist<<<NWG, TPB, 0, stream>>>(pa);

    k_readout<<<(SS*BB*NN)/128, 256, 0, stream>>>(traj, rW1, rb1, rW2, rb2, outr);
}

// Round 9
// 1175.276 us; speedup vs baseline: 3.1027x; 1.4819x over previous
//
#include <hip/hip_runtime.h>
#include <hip/hip_fp8.h>
#include <math.h>

typedef __attribute__((ext_vector_type(4))) float f32x4;

#define NN   4096
#define BB   8
#define DD   8
#define SS   16
#define KSUB 4
#define IND  16
#define NWG  256
#define TPB  1024
#define HSZ  (64 * 4096)           // one rotating h buffer (fp8), 256 KB
#define GSCALE 1.52587890625e-5f   // 2^-16 (A stored as fp8 of A*2^16)

__device__ __forceinline__ float fsig(float x) {
    return __builtin_amdgcn_rcpf(1.f + __expf(-x));
}
__device__ __forceinline__ float ftanh(float x) {
    x = fminf(fmaxf(x, -15.f), 15.f);
    float e = __expf(2.f * x);
    return (e - 1.f) * __builtin_amdgcn_rcpf(e + 1.f);
}
__device__ __forceinline__ unsigned char f2fp8(float x) {
    return __hip_cvt_float_to_fp8(x, __HIP_SATFINITE, __HIP_E4M3);
}

// ---------------------------------------------------------------------------
// A (fp32) -> A8 (fp8 e4m3 of A*65536), and zero the barrier region (2048 u32)
// ---------------------------------------------------------------------------
__global__ __launch_bounds__(256) void k_convA8(const float* __restrict__ A,
                                                unsigned char* __restrict__ A8,
                                                unsigned int* __restrict__ cnt) {
    if (blockIdx.x == 0)
        for (int idx = threadIdx.x; idx < 2048; idx += 256) cnt[idx] = 0u;
    size_t i = ((size_t)blockIdx.x * 256 + threadIdx.x) * 8;
    float4 v0 = *reinterpret_cast<const float4*>(A + i);
    float4 v1 = *reinterpret_cast<const float4*>(A + i + 4);
    unsigned char o[8];
    o[0] = f2fp8(v0.x * 65536.f); o[1] = f2fp8(v0.y * 65536.f);
    o[2] = f2fp8(v0.z * 65536.f); o[3] = f2fp8(v0.w * 65536.f);
    o[4] = f2fp8(v1.x * 65536.f); o[5] = f2fp8(v1.y * 65536.f);
    o[6] = f2fp8(v1.z * 65536.f); o[7] = f2fp8(v1.w * 65536.f);
    *reinterpret_cast<unsigned long long*>(&A8[i]) =
        *reinterpret_cast<const unsigned long long*>(o);
}

// ---------------------------------------------------------------------------
// Hierarchical grid barrier: 8 spread arrival counters, single combiner,
// 8 per-group epoch mirrors. No L2 writeback. h-state crossed XCDs via
// agent-scope atomic stores before this; every wave drains vmcnt first.
// ---------------------------------------------------------------------------
__device__ __forceinline__ void gbar3(unsigned int* cnt, int wg, int tid,
                                      unsigned int epoch) {
    unsigned int* ep = cnt + 1024;           // mirrors live 4 KB above counters
    asm volatile("s_waitcnt vmcnt(0)" ::: "memory");
    __syncthreads();
    if (wg == 0) {
        if (tid == 0) {
            __hip_atomic_fetch_add(&cnt[0], 1u, __ATOMIC_RELAXED, __HIP_MEMORY_SCOPE_AGENT);
            for (;;) {
                unsigned int s = 0;
#pragma unroll
                for (int i = 0; i < 8; ++i)
                    s += __hip_atomic_load(&cnt[i * 32], __ATOMIC_RELAXED, __HIP_MEMORY_SCOPE_AGENT);
                if (s >= (unsigned int)NWG * epoch) break;
                __builtin_amdgcn_s_sleep(0);
            }
#pragma unroll
            for (int i = 0; i < 8; ++i)
                __hip_atomic_store(&ep[i * 32], epoch, __ATOMIC_RELAXED, __HIP_MEMORY_SCOPE_AGENT);
        }
    } else if (tid == 0) {
        __hip_atomic_fetch_add(&cnt[(wg & 7) * 32], 1u, __ATOMIC_RELAXED, __HIP_MEMORY_SCOPE_AGENT);
        while (__hip_atomic_load(&ep[(wg & 7) * 32], __ATOMIC_RELAXED, __HIP_MEMORY_SCOPE_AGENT) < epoch)
            __builtin_amdgcn_s_sleep(1);
    }
    __syncthreads();
    asm volatile("" ::: "memory");
}

// ---------------------------------------------------------------------------
// Persistent kernel: prep + 60 substeps. 256 WGs x 1024 thr (1 WG/CU).
// h8 buffers are BLOCKED: [jblk=node/16][c=64][j16=16] (1 KB per node-block)
// so each WG's stores are 1 KB contiguous and GEMM reads are full-line.
// ---------------------------------------------------------------------------
struct PArgs {
    const unsigned char* A8;
    const float *times, *x_all, *z_all, *h0;
    const float *dW1, *db1, *dW2, *db2;
    const float *fW1, *fb1, *fW2, *fb2;
    const float *pW1, *pb1, *pW2, *pb2;
    float* traj;
    unsigned char* h8;       // 61 rotating buffers of HSZ (blocked layout)
    unsigned int* cnt;
};

__global__ __launch_bounds__(TPB, 4) void k_persist(PArgs p) {
    __shared__ __align__(16) unsigned char ls_A8[16 * 4096];   // 64 KB, swizzled
    __shared__ float ls_part[8][16][68];    // 34.8 KB
    __shared__ float ls_hold[16][68];       // persistent h tile (fp32)
    __shared__ __align__(8) unsigned char ls_h8st[64][16];     // packed h8 staging
    __shared__ float ls_dW1T[64][12]; __shared__ float ls_fW1T[64][12];
    __shared__ float ls_dW2[64][8];   __shared__ float ls_fW2[64][8];
    __shared__ float ls_pW1T[64][24]; __shared__ float ls_pW2[64][8];
    __shared__ float ls_db1[64];  __shared__ float ls_fb1[64];  __shared__ float ls_pb1[64];
    __shared__ float ls_db2[8];   __shared__ float ls_fb2[8];   __shared__ float ls_pb2[8];
    __shared__ float ls_times[SS];

    const int tid = threadIdx.x;
    const int wg  = blockIdx.x;
    const int i0  = (((wg & 7) << 5) | (wg >> 3)) << 4;   // XCD-contiguous 16-node tile
    const size_t myblk = (size_t)(i0 >> 4) << 10;         // byte offset of this WG's block

    // ---- stage weights (once) ----
    for (int idx = tid; idx < 9*64; idx += TPB) {
        int d = idx >> 6, j = idx & 63;
        ls_dW1T[j][d] = p.dW1[idx]; ls_fW1T[j][d] = p.fW1[idx];
    }
    for (int idx = tid; idx < 64*8; idx += TPB) {
        ls_dW2[idx>>3][idx&7] = p.dW2[idx]; ls_fW2[idx>>3][idx&7] = p.fW2[idx];
        ls_pW2[idx>>3][idx&7] = p.pW2[idx];
    }
    for (int idx = tid; idx < 24*64; idx += TPB) ls_pW1T[idx&63][idx>>6] = p.pW1[idx];
    if (tid < 64) { ls_db1[tid] = p.db1[tid]; ls_fb1[tid] = p.fb1[tid]; ls_pb1[tid] = p.pb1[tid]; }
    else if (tid < 72) { ls_db2[tid-64] = p.db2[tid-64]; ls_fb2[tid-64] = p.fb2[tid-64]; ls_pb2[tid-64] = p.pb2[tid-64]; }
    else if (tid >= 128 && tid < 128 + SS) ls_times[tid-128] = p.times[tid-128];

    // ---- stage A rows into LDS (once), XOR-swizzled ----
    for (int it = 0; it < 8; ++it) {
        int gi = (it * TPB + tid) * 8;          // byte index within 16x4096
        int node = gi >> 12, k = gi & 4095;
        unsigned long long v = *reinterpret_cast<const unsigned long long*>(
            p.A8 + (size_t)(i0 + node) * NN + k);
        *reinterpret_cast<unsigned long long*>(
            &ls_A8[(node << 12) + (k ^ ((node & 15) << 3))]) = v;
    }
    __syncthreads();

    const int q = tid & 7, row = tid >> 3;   // 128 rows, 8 threads each
    const int node = row & 15, b = row >> 4;

    // ---- prep: traj[0] = h0 ; hold = h0 + pert(x[0], h0) -> h8[0] ----
    {
        const float* hp = p.h0 + ((size_t)b * NN + i0 + node) * DD;
        float4 h0a = *reinterpret_cast<const float4*>(hp);
        float4 h0b = *reinterpret_cast<const float4*>(hp + 4);
        float hv[8] = {h0a.x,h0a.y,h0a.z,h0a.w,h0b.x,h0b.y,h0b.z,h0b.w};
        p.traj[((size_t)b * NN + i0 + node) * DD + q] = hv[q];

        float xin[24];
        const float* xp = p.x_all + ((size_t)b * NN + i0 + node) * IND;  // s=0
        float4 x0 = *reinterpret_cast<const float4*>(xp);
        float4 x1 = *reinterpret_cast<const float4*>(xp + 4);
        float4 x2 = *reinterpret_cast<const float4*>(xp + 8);
        float4 x3 = *reinterpret_cast<const float4*>(xp + 12);
        xin[0]=x0.x; xin[1]=x0.y; xin[2]=x0.z; xin[3]=x0.w;
        xin[4]=x1.x; xin[5]=x1.y; xin[6]=x1.z; xin[7]=x1.w;
        xin[8]=x2.x; xin[9]=x2.y; xin[10]=x2.z; xin[11]=x2.w;
        xin[12]=x3.x; xin[13]=x3.y; xin[14]=x3.z; xin[15]=x3.w;
#pragma unroll
        for (int d = 0; d < 8; ++d) xin[16+d] = hv[d];

        float ap[8] = {0,0,0,0,0,0,0,0};
#pragma unroll
        for (int jj = 0; jj < 8; ++jj) {
            const int j = q + (jj << 3);
            float s1 = ls_pb1[j];
#pragma unroll
            for (int c4 = 0; c4 < 6; ++c4) {
                f32x4 wv = *reinterpret_cast<const f32x4*>(&ls_pW1T[j][c4*4]);
#pragma unroll
                for (int r = 0; r < 4; ++r) s1 += xin[c4*4+r] * wv[r];
            }
            s1 = fmaxf(s1, 0.f);
            f32x4 w2a = *reinterpret_cast<const f32x4*>(&ls_pW2[j][0]);
            f32x4 w2b = *reinterpret_cast<const f32x4*>(&ls_pW2[j][4]);
#pragma unroll
            for (int r = 0; r < 4; ++r) { ap[r] += s1*w2a[r]; ap[4+r] += s1*w2b[r]; }
        }
        float aps[8];
#pragma unroll
        for (int d = 0; d < 8; ++d) {
            float t = ap[d];
            t += __shfl_xor(t, 1); t += __shfl_xor(t, 2); t += __shfl_xor(t, 4);
            aps[d] = t;
        }
        float outp = hv[q] + aps[q] + ls_pb2[q];
        ls_hold[node][b*8 + q] = outp;
        ls_h8st[b*8 + q][node] = f2fp8(outp);
    }
    // pre-load z for substep 0 (latency hides under barrier)
    float4 zn0, zn1;
    {
        const size_t zb = ((size_t)b)*((size_t)NN*DD) + (size_t)(i0+node)*DD;
        zn0 = *reinterpret_cast<const float4*>(p.z_all + zb);
        zn1 = *reinterpret_cast<const float4*>(p.z_all + zb + 4);
    }
    __syncthreads();
    if (tid < 128) {    // 128 x 8B contiguous agent-scope stores (full lines)
        int c = tid >> 1, j8 = (tid & 1) << 3;
        unsigned long long v = *reinterpret_cast<const unsigned long long*>(&ls_h8st[c][j8]);
        __hip_atomic_store(reinterpret_cast<unsigned long long*>(
            p.h8 + myblk + (c << 4) + j8), v,
            __ATOMIC_RELAXED, __HIP_MEMORY_SCOPE_AGENT);
    }
    gbar3(p.cnt, wg, tid, 1u);

    // ---- 60 substeps ----
    for (int g = 0; g < (SS-1)*KSUB; ++g) {
        const int s = g >> 2, k = g & 3;
        const unsigned char* hin  = p.h8 + (size_t)g * HSZ;
        unsigned char*       hout = p.h8 + (size_t)(g+1) * HSZ;

        const float t0 = ls_times[s], t1 = ls_times[s+1];
        const float dt = (t1 - t0) * 0.25f;
        const float tk = t0 + (float)k * dt;
        const float sqdt = sqrtf(dt);
        const bool dopert = (k == 3) && (s < SS - 2);

        // ---- GEMM: h_graph partials; wave = 256-wide K chunk, fp8 MFMA ----
        {
            const int wave = tid >> 6, lane = tid & 63;
            const int k0 = wave << 8;
            const int lrow = lane & 15;
            const int ksub = (lane >> 4) << 3;
            const int abase = lrow << 12;
            const int axor  = (lrow & 15) << 3;
            f32x4 acc[4];
#pragma unroll
            for (int ct = 0; ct < 4; ++ct) acc[ct] = (f32x4){0.f,0.f,0.f,0.f};
#pragma unroll
            for (int kk = 0; kk < 8; ++kk) {
                const int koff = k0 + kk*32 + ksub;
                long bfr = *reinterpret_cast<const long*>(&ls_A8[abase + (koff ^ axor)]);
                const size_t hb = ((size_t)(koff >> 4) << 10) + (koff & 15);
#pragma unroll
                for (int ct = 0; ct < 4; ++ct) {
                    long av = *reinterpret_cast<const long*>(
                        hin + hb + ((ct*16 + lrow) << 4));
                    acc[ct] = __builtin_amdgcn_mfma_f32_16x16x32_fp8_fp8(
                        av, bfr, acc[ct], 0, 0, 0);
                }
            }
            const int rb = (lane >> 4) << 2;
            if (wave < 8) {
#pragma unroll
                for (int ct = 0; ct < 4; ++ct)
#pragma unroll
                    for (int r = 0; r < 4; ++r)
                        ls_part[wave][lrow][ct*16 + rb + r] = acc[ct][r];
            }
            __syncthreads();
            if (wave >= 8) {
#pragma unroll
                for (int ct = 0; ct < 4; ++ct)
#pragma unroll
                    for (int r = 0; r < 4; ++r)
                        ls_part[wave-8][lrow][ct*16 + rb + r] += acc[ct][r];
            }
            __syncthreads();
        }

        // ---- per-(b,node) MLPs: 8 threads/row ----
        float ing[9], inh[9];
        {
            f32x4 g0 = (f32x4){0,0,0,0}, g1 = (f32x4){0,0,0,0};
#pragma unroll
            for (int w = 0; w < 8; ++w) {
                g0 += *reinterpret_cast<const f32x4*>(&ls_part[w][node][b*8]);
                g1 += *reinterpret_cast<const f32x4*>(&ls_part[w][node][b*8+4]);
            }
            f32x4 h0v = *reinterpret_cast<const f32x4*>(&ls_hold[node][b*8]);
            f32x4 h1v = *reinterpret_cast<const f32x4*>(&ls_hold[node][b*8+4]);
#pragma unroll
            for (int r = 0; r < 4; ++r) {
                ing[r] = g0[r]*GSCALE; ing[4+r] = g1[r]*GSCALE;
                inh[r] = h0v[r];       inh[4+r] = h1v[r];
            }
        }
        ing[8] = tk; inh[8] = tk;
        float adr[8] = {0,0,0,0,0,0,0,0}, adf[8] = {0,0,0,0,0,0,0,0};
#pragma unroll
        for (int jj = 0; jj < 8; ++jj) {
            const int j = q + (jj << 3);
            f32x4 w1a = *reinterpret_cast<const f32x4*>(&ls_dW1T[j][0]);
            f32x4 w1b = *reinterpret_cast<const f32x4*>(&ls_dW1T[j][4]);
            float w1t = ls_dW1T[j][8];
            f32x4 v1a = *reinterpret_cast<const f32x4*>(&ls_fW1T[j][0]);
            f32x4 v1b = *reinterpret_cast<const f32x4*>(&ls_fW1T[j][4]);
            float v1t = ls_fW1T[j][8];
            float s1 = ls_db1[j], s2 = ls_fb1[j];
#pragma unroll
            for (int r = 0; r < 4; ++r) {
                s1 += ing[r]*w1a[r] + ing[4+r]*w1b[r];
                s2 += inh[r]*v1a[r] + inh[4+r]*v1b[r];
            }
            s1 += ing[8]*w1t; s2 += inh[8]*v1t;
            float th = ftanh(s1), sg = fsig(s2);
            f32x4 w2a = *reinterpret_cast<const f32x4*>(&ls_dW2[j][0]);
            f32x4 w2b = *reinterpret_cast<const f32x4*>(&ls_dW2[j][4]);
            f32x4 v2a = *reinterpret_cast<const f32x4*>(&ls_fW2[j][0]);
            f32x4 v2b = *reinterpret_cast<const f32x4*>(&ls_fW2[j][4]);
#pragma unroll
            for (int r = 0; r < 4; ++r) {
                adr[r] += th*w2a[r]; adr[4+r] += th*w2b[r];
                adf[r] += sg*v2a[r]; adf[4+r] += sg*v2b[r];
            }
        }
#pragma unroll
        for (int d = 0; d < 8; ++d) {
            adr[d] += __shfl_xor(adr[d], 1); adr[d] += __shfl_xor(adr[d], 2); adr[d] += __shfl_xor(adr[d], 4);
            adf[d] += __shfl_xor(adf[d], 1); adf[d] += __shfl_xor(adf[d], 2); adf[d] += __shfl_xor(adf[d], 4);
        }
        float zz[8] = {zn0.x, zn0.y, zn0.z, zn0.w, zn1.x, zn1.y, zn1.z, zn1.w};
        float hnew[8];
#pragma unroll
        for (int d = 0; d < 8; ++d) {
            float dr  = adr[d] + ls_db2[d];
            float dif = 0.1f * fsig(adf[d] + ls_fb2[d]);
            hnew[d] = inh[d] + dr * dt + dif * (sqdt * zz[d]);
        }

        if (k == 3) {
            p.traj[((size_t)((s+1)*BB + b))*((size_t)NN*DD) + (size_t)(i0+node)*DD + q] = hnew[q];
        }
        float outv;
        if (dopert) {
            float xin[24];
            const float* xp = p.x_all + ((size_t)(s+1)*BB + b)*((size_t)NN*IND) + (size_t)(i0+node)*IND;
            float4 x0 = *reinterpret_cast<const float4*>(xp);
            float4 x1 = *reinterpret_cast<const float4*>(xp + 4);
            float4 x2 = *reinterpret_cast<const float4*>(xp + 8);
            float4 x3 = *reinterpret_cast<const float4*>(xp + 12);
            xin[0]=x0.x; xin[1]=x0.y; xin[2]=x0.z; xin[3]=x0.w;
            xin[4]=x1.x; xin[5]=x1.y; xin[6]=x1.z; xin[7]=x1.w;
            xin[8]=x2.x; xin[9]=x2.y; xin[10]=x2.z; xin[11]=x2.w;
            xin[12]=x3.x; xin[13]=x3.y; xin[14]=x3.z; xin[15]=x3.w;
#pragma unroll
            for (int d = 0; d < 8; ++d) xin[16+d] = hnew[d];
            float ap[8] = {0,0,0,0,0,0,0,0};
#pragma unroll
            for (int jj = 0; jj < 8; ++jj) {
                const int j = q + (jj << 3);
                float s1 = ls_pb1[j];
#pragma unroll
                for (int c4 = 0; c4 < 6; ++c4) {
                    f32x4 wv = *reinterpret_cast<const f32x4*>(&ls_pW1T[j][c4*4]);
#pragma unroll
                    for (int r = 0; r < 4; ++r) s1 += xin[c4*4+r] * wv[r];
                }
                s1 = fmaxf(s1, 0.f);
                f32x4 w2a = *reinterpret_cast<const f32x4*>(&ls_pW2[j][0]);
                f32x4 w2b = *reinterpret_cast<const f32x4*>(&ls_pW2[j][4]);
#pragma unroll
                for (int r = 0; r < 4; ++r) { ap[r] += s1*w2a[r]; ap[4+r] += s1*w2b[r]; }
            }
            float aps[8];
#pragma unroll
            for (int d = 0; d < 8; ++d) {
                float t = ap[d];
                t += __shfl_xor(t, 1); t += __shfl_xor(t, 2); t += __shfl_xor(t, 4);
                aps[d] = t;
            }
            outv = hnew[q] + aps[q] + ls_pb2[q];
        } else {
            outv = hnew[q];
        }
        ls_hold[node][b*8 + q] = outv;
        ls_h8st[b*8 + q][node] = f2fp8(outv);

        // prefetch z for next substep (completes under the barrier)
        if (g + 1 < (SS-1)*KSUB) {
            const size_t zb = ((size_t)((g+1)*BB + b))*((size_t)NN*DD) + (size_t)(i0+node)*DD;
            zn0 = *reinterpret_cast<const float4*>(p.z_all + zb);
            zn1 = *reinterpret_cast<const float4*>(p.z_all + zb + 4);
        }
        if (g < (SS-1)*KSUB - 1) {
            __syncthreads();
            if (tid < 128) {
                int c = tid >> 1, j8 = (tid & 1) << 3;
                unsigned long long v = *reinterpret_cast<const unsigned long long*>(&ls_h8st[c][j8]);
                __hip_atomic_store(reinterpret_cast<unsigned long long*>(
                    hout + myblk + (c << 4) + j8), v,
                    __ATOMIC_RELAXED, __HIP_MEMORY_SCOPE_AGENT);
            }
            gbar3(p.cnt, wg, tid, (unsigned int)(g + 2));
        }
    }
}

// ---------------------------------------------------------------------------
// readout: relu(traj @ rW1 + rb1) @ rW2 + rb2 ; 2 threads/row (16 outs each)
// ---------------------------------------------------------------------------
__global__ __launch_bounds__(256) void k_readout(
    const float* __restrict__ traj,
    const float* __restrict__ rW1, const float* __restrict__ rb1,
    const float* __restrict__ rW2, const float* __restrict__ rb2,
    float* __restrict__ outr)
{
    __shared__ float ls_W1T[64][12];
    __shared__ float ls_W2[64][32];
    __shared__ float ls_b1[64];    __shared__ float ls_b2[32];
    const int tid = threadIdx.x;
    for (int idx = tid; idx < 8*64;  idx += 256) ls_W1T[idx&63][idx>>6] = rW1[idx];
    for (int idx = tid; idx < 64*32; idx += 256) ls_W2[idx>>5][idx&31] = rW2[idx];
    if (tid < 64) ls_b1[tid] = rb1[tid];
    else if (tid < 96) ls_b2[tid-64] = rb2[tid-64];
    __syncthreads();

    const int half = tid & 1, ob = half << 4;
    const size_t row = (size_t)blockIdx.x * 128 + (tid >> 1);
    const float4* pi = reinterpret_cast<const float4*>(traj + row*8);
    float4 a0 = pi[0], a1 = pi[1];
    float in[8] = {a0.x,a0.y,a0.z,a0.w,a1.x,a1.y,a1.z,a1.w};
    float out[16];
#pragma unroll
    for (int o4 = 0; o4 < 4; ++o4) {
        f32x4 bv = *reinterpret_cast<const f32x4*>(&ls_b2[ob + o4*4]);
#pragma unroll
        for (int r = 0; r < 4; ++r) out[o4*4+r] = bv[r];
    }
    for (int j = 0; j < 64; ++j) {
        f32x4 w1a = *reinterpret_cast<const f32x4*>(&ls_W1T[j][0]);
        f32x4 w1b = *reinterpret_cast<const f32x4*>(&ls_W1T[j][4]);
        float s1 = ls_b1[j];
#pragma unroll
        for (int r = 0; r < 4; ++r) s1 += in[r]*w1a[r] + in[4+r]*w1b[r];
        s1 = fmaxf(s1, 0.f);
#pragma unroll
        for (int o4 = 0; o4 < 4; ++o4) {
            f32x4 w2 = *reinterpret_cast<const f32x4*>(&ls_W2[j][ob + o4*4]);
#pragma unroll
            for (int r = 0; r < 4; ++r) out[o4*4+r] += s1 * w2[r];
        }
    }
    float* op = outr + row*32 + ob;
#pragma unroll
    for (int o4 = 0; o4 < 4; ++o4) {
        float4 v = {out[o4*4], out[o4*4+1], out[o4*4+2], out[o4*4+3]};
        *reinterpret_cast<float4*>(op + o4*4) = v;
    }
}

// ---------------------------------------------------------------------------
extern "C" void kernel_launch(void* const* d_in, const int* in_sizes, int n_in,
                              void* d_out, int out_size, void* d_ws, size_t ws_size,
                              hipStream_t stream) {
    (void)in_sizes; (void)n_in; (void)out_size; (void)ws_size;
    const float* times = (const float*)d_in[0];
    const float* x_all = (const float*)d_in[1];
    const float* h0    = (const float*)d_in[2];
    const float* Amat  = (const float*)d_in[3];
    const float* z_all = (const float*)d_in[4];
    const float* dW1 = (const float*)d_in[5],  *db1 = (const float*)d_in[6];
    const float* dW2 = (const float*)d_in[7],  *db2 = (const float*)d_in[8];
    const float* fW1 = (const float*)d_in[9],  *fb1 = (const float*)d_in[10];
    const float* fW2 = (const float*)d_in[11], *fb2 = (const float*)d_in[12];
    const float* pW1 = (const float*)d_in[13], *pb1 = (const float*)d_in[14];
    const float* pW2 = (const float*)d_in[15], *pb2 = (const float*)d_in[16];
    const float* rW1 = (const float*)d_in[17], *rb1 = (const float*)d_in[18];
    const float* rW2 = (const float*)d_in[19], *rb2 = (const float*)d_in[20];

    float* traj = (float*)d_out;                      // [16,8,4096,8]
    float* outr = traj + (size_t)SS*BB*NN*DD;         // [16,8,4096,32]

    char* ws = (char*)d_ws;
    unsigned char* A8  = (unsigned char*)ws;                 // 16 MB
    unsigned char* h8  = (unsigned char*)(ws + (16u << 20)); // 61 x 256 KB (blocked)
    unsigned int*  cnt = (unsigned int*)(ws + (35u << 20));  // counters+mirrors (8 KB)

    k_convA8<<<NN*NN/(256*8), 256, 0, stream>>>(Amat, A8, cnt);

    PArgs pa;
    pa.A8 = A8; pa.times = times; pa.x_all = x_all; pa.z_all = z_all; pa.h0 = h0;
    pa.dW1 = dW1; pa.db1 = db1; pa.dW2 = dW2; pa.db2 = db2;
    pa.fW1 = fW1; pa.fb1 = fb1; pa.fW2 = fW2; pa.fb2 = fb2;
    pa.pW1 = pW1; pa.pb1 = pb1; pa.pW2 = pW2; pa.pb2 = pb2;
    pa.traj = traj; pa.h8 = h8; pa.cnt = cnt;
    k_persist<<<NWG, TPB, 0, stream>>>(pa);

    k_readout<<<(SS*BB*NN)/128, 256, 0, stream>>>(traj, rW1, rb1, rW2, rb2, outr);
}